// Round 10
// baseline (2515.340 us; speedup 1.0000x reference)
//
#include <hip/hip_runtime.h>
#include <hip/hip_bf16.h>
#include <math.h>

#define L_TOK 1569
#define DM 192
#define DI 384
#define DS 16
#define DTR 12
#define DCONV 4
#define XDBL_N (DTR + 2*DS)   // 44
#define DEPTH 8
#define NCHUNK 25
#define CLEN 64
#define NPATCH 1568

typedef __attribute__((ext_vector_type(8))) short short8;
typedef __attribute__((ext_vector_type(4))) float f32x4;

__device__ __forceinline__ unsigned short f2bf(float f) {
  unsigned int u = __float_as_uint(f);
  u += 0x7FFFu + ((u >> 16) & 1u);   // round-to-nearest-even
  return (unsigned short)(u >> 16);
}

// ---------------------------------------------------------------------------
// im2col + cur init (pos + bias/cls).
// ---------------------------------------------------------------------------
__global__ __launch_bounds__(256) void im2col_kernel(
    const float* __restrict__ x, const float* __restrict__ cls,
    const float* __restrict__ pb, const float* __restrict__ pos,
    float* __restrict__ px, float* __restrict__ curp) {
  int gid = blockIdx.x * 256 + threadIdx.x;
  const int initN = (L_TOK * DM) / 4;
  if (gid < initN) {
    int e4 = gid * 4;
    int tok = e4 / DM;
    int col = e4 % DM;
    float4 pv = *(const float4*)(pos + e4);
    float4 av = (tok == 0) ? *(const float4*)(cls + col)
                           : *(const float4*)(pb + col);
    float4 o = {pv.x + av.x, pv.y + av.y, pv.z + av.z, pv.w + av.w};
    *(float4*)(curp + e4) = o;
  }
  if (gid >= NPATCH * 192) return;
  int patch = gid / 192;
  int r = gid % 192;
  int c = r / 64;
  int p = (r >> 2) & 15;
  int q = (r & 3) * 4;
  int t = patch / 196, hw = patch % 196, hh = hw / 14, w = hw % 14;
  const float* src = x + ((size_t)(c*8 + t)*224 + hh*16 + p)*224 + w*16 + q;
  *(float4*)(px + (size_t)patch*768 + r*4) = *(const float4*)src;
}

// ---------------------------------------------------------------------------
// Final LayerNorm. One wave per token.
// ---------------------------------------------------------------------------
__global__ __launch_bounds__(64) void ln_kernel(
    const float* __restrict__ in, float* __restrict__ out,
    const float* __restrict__ g, const float* __restrict__ b) {
  int tokn = blockIdx.x;
  int lane = threadIdx.x;
  const float* row = in + (size_t)tokn*DM;
  float x0 = row[lane], x1 = row[lane+64], x2 = row[lane+128];
  float s = x0 + x1 + x2;
  float s2 = x0*x0 + x1*x1 + x2*x2;
#pragma unroll
  for (int off = 1; off < 64; off <<= 1) {
    s  += __shfl_xor(s,  off, 64);
    s2 += __shfl_xor(s2, off, 64);
  }
  float m = s * (1.0f/192.0f);
  float v = s2 * (1.0f/192.0f) - m*m;
  float rs = rsqrtf(v + 1e-5f);
  float* orow = out + (size_t)tokn*DM;
  orow[lane]     = (x0 - m)*rs*g[lane]     + b[lane];
  orow[lane+64]  = (x1 - m)*rs*g[lane+64]  + b[lane+64];
  orow[lane+128] = (x2 - m)*rs*g[lane+128] + b[lane+128];
}

// ---------------------------------------------------------------------------
// Fused LN + xz GEMM (K=192 fully in LDS, one barrier before 6 MFMA k-steps).
// ---------------------------------------------------------------------------
__global__ __launch_bounds__(256) void lnxz_kernel(
    const float* __restrict__ cur, const float* __restrict__ g,
    const float* __restrict__ b, const float* __restrict__ W,
    float* __restrict__ xz) {
  __shared__ unsigned short As[64][200];
  __shared__ unsigned short Bs[64][200];
  __shared__ float gs[192], bs2[192];
  int tid = threadIdx.x;
  int m0 = blockIdx.y * 64, n0 = blockIdx.x * 64;
  int wave = tid >> 6, lane = tid & 63;
  int wr = wave >> 1, wc = wave & 1;
  int l15 = lane & 15, lk = (lane >> 4) * 8;

  for (int i = tid; i < 192; i += 256) { gs[i] = g[i]; bs2[i] = b[i]; }

  int r = tid >> 2, c0 = (tid & 3) * 48;
  float v[48];
  {
    int row = m0 + r;
    if (row < L_TOK) {
      const float* rp = cur + (size_t)row*DM + c0;
#pragma unroll
      for (int j = 0; j < 12; ++j) {
        float4 t4 = *(const float4*)(rp + j*4);
        v[j*4+0]=t4.x; v[j*4+1]=t4.y; v[j*4+2]=t4.z; v[j*4+3]=t4.w;
      }
    } else {
#pragma unroll
      for (int j = 0; j < 48; ++j) v[j] = 0.f;
    }
  }
  float s = 0.f, s2 = 0.f;
#pragma unroll
  for (int j = 0; j < 48; ++j) { s += v[j]; s2 += v[j]*v[j]; }
  s  += __shfl_xor(s, 1, 64); s2 += __shfl_xor(s2, 1, 64);
  s  += __shfl_xor(s, 2, 64); s2 += __shfl_xor(s2, 2, 64);
  float mu = s * (1.0f/192.0f);
  float var = s2 * (1.0f/192.0f) - mu*mu;
  float rsd = rsqrtf(var + 1e-5f);

  __syncthreads();
#pragma unroll
  for (int j = 0; j < 48; ++j) {
    int k = c0 + j;
    As[r][k] = f2bf((v[j] - mu)*rsd*gs[k] + bs2[k]);
  }
  {
    const float* rp = W + (size_t)(n0 + r)*DM + c0;
#pragma unroll
    for (int j = 0; j < 12; ++j) {
      float4 t4 = *(const float4*)(rp + j*4);
      Bs[r][c0+j*4+0]=f2bf(t4.x); Bs[r][c0+j*4+1]=f2bf(t4.y);
      Bs[r][c0+j*4+2]=f2bf(t4.z); Bs[r][c0+j*4+3]=f2bf(t4.w);
    }
  }
  __syncthreads();

  f32x4 acc[2][2];
#pragma unroll
  for (int i = 0; i < 2; ++i)
#pragma unroll
    for (int j = 0; j < 2; ++j) acc[i][j] = (f32x4){0.f,0.f,0.f,0.f};

#pragma unroll
  for (int kk = 0; kk < 6; ++kk) {
    short8 af0 = *(const short8*)&As[wr*32      + l15][kk*32 + lk];
    short8 af1 = *(const short8*)&As[wr*32 + 16 + l15][kk*32 + lk];
    short8 bf0 = *(const short8*)&Bs[wc*32      + l15][kk*32 + lk];
    short8 bf1 = *(const short8*)&Bs[wc*32 + 16 + l15][kk*32 + lk];
    acc[0][0] = __builtin_amdgcn_mfma_f32_16x16x32_bf16(af0, bf0, acc[0][0], 0, 0, 0);
    acc[0][1] = __builtin_amdgcn_mfma_f32_16x16x32_bf16(af0, bf1, acc[0][1], 0, 0, 0);
    acc[1][0] = __builtin_amdgcn_mfma_f32_16x16x32_bf16(af1, bf0, acc[1][0], 0, 0, 0);
    acc[1][1] = __builtin_amdgcn_mfma_f32_16x16x32_bf16(af1, bf1, acc[1][1], 0, 0, 0);
  }

#pragma unroll
  for (int rr = 0; rr < 2; ++rr) {
#pragma unroll
    for (int cc = 0; cc < 2; ++cc) {
      int col = n0 + wc*32 + cc*16 + l15;
      int rowb = m0 + wr*32 + rr*16 + (lane >> 4)*4;
#pragma unroll
      for (int j = 0; j < 4; ++j) {
        int row = rowb + j;
        if (row < L_TOK) xz[(size_t)row*(2*DI) + col] = acc[rr][cc][j];
      }
    }
  }
}

// ---------------------------------------------------------------------------
// MFMA bf16 GEMM with split-K (patch embed only); atomicAdd into pre-init C.
// ---------------------------------------------------------------------------
__global__ __launch_bounds__(256) void mgemm_kernel(
    const float* __restrict__ A, int lda,
    const float* __restrict__ B, int ldb,
    float* __restrict__ C, int ldc,
    int M, int N, int ksl) {
  __shared__ unsigned short As[64*40];
  __shared__ unsigned short Bs[64*40];
  int tid = threadIdx.x;
  int m0 = blockIdx.y * 64, n0 = blockIdx.x * 64;
  int kbase = blockIdx.z * ksl;
  int wave = tid >> 6, lane = tid & 63;
  int wr = wave >> 1, wc = wave & 1;
  int srow = tid >> 2;
  int skq  = (tid & 3) * 8;
  f32x4 acc[2][2];
#pragma unroll
  for (int i = 0; i < 2; ++i)
#pragma unroll
    for (int j = 0; j < 2; ++j) acc[i][j] = (f32x4){0.f,0.f,0.f,0.f};

  int am = m0 + srow;
  int bn = n0 + srow;
  bool a_ok = (am < M), b_ok = (bn < N);
  const float* ap = A + (size_t)am*lda + kbase + skq;
  const float* bp = B + (size_t)bn*ldb + kbase + skq;
  const float4 z4 = {0.f,0.f,0.f,0.f};
  int l15 = lane & 15, lk = (lane >> 4) * 8;

  int nt = ksl >> 5;
  float4 a0 = a_ok ? *(const float4*)(ap)     : z4;
  float4 a1 = a_ok ? *(const float4*)(ap + 4) : z4;
  float4 b0 = b_ok ? *(const float4*)(bp)     : z4;
  float4 b1 = b_ok ? *(const float4*)(bp + 4) : z4;

  for (int i = 0; i < nt; ++i) {
    {
      short8 pa, pb;
      pa[0]=f2bf(a0.x); pa[1]=f2bf(a0.y); pa[2]=f2bf(a0.z); pa[3]=f2bf(a0.w);
      pa[4]=f2bf(a1.x); pa[5]=f2bf(a1.y); pa[6]=f2bf(a1.z); pa[7]=f2bf(a1.w);
      pb[0]=f2bf(b0.x); pb[1]=f2bf(b0.y); pb[2]=f2bf(b0.z); pb[3]=f2bf(b0.w);
      pb[4]=f2bf(b1.x); pb[5]=f2bf(b1.y); pb[6]=f2bf(b1.z); pb[7]=f2bf(b1.w);
      *(short8*)&As[srow*40 + skq] = pa;
      *(short8*)&Bs[srow*40 + skq] = pb;
    }
    __syncthreads();
    bool pf = (i + 1 < nt);
    int k0n = (i + 1) << 5;
    a0 = (pf && a_ok) ? *(const float4*)(ap + k0n)     : z4;
    a1 = (pf && a_ok) ? *(const float4*)(ap + k0n + 4) : z4;
    b0 = (pf && b_ok) ? *(const float4*)(bp + k0n)     : z4;
    b1 = (pf && b_ok) ? *(const float4*)(bp + k0n + 4) : z4;

    short8 af0 = *(const short8*)&As[(wr*32      + l15)*40 + lk];
    short8 af1 = *(const short8*)&As[(wr*32 + 16 + l15)*40 + lk];
    short8 bf0 = *(const short8*)&Bs[(wc*32      + l15)*40 + lk];
    short8 bf1 = *(const short8*)&Bs[(wc*32 + 16 + l15)*40 + lk];
    acc[0][0] = __builtin_amdgcn_mfma_f32_16x16x32_bf16(af0, bf0, acc[0][0], 0, 0, 0);
    acc[0][1] = __builtin_amdgcn_mfma_f32_16x16x32_bf16(af0, bf1, acc[0][1], 0, 0, 0);
    acc[1][0] = __builtin_amdgcn_mfma_f32_16x16x32_bf16(af1, bf0, acc[1][0], 0, 0, 0);
    acc[1][1] = __builtin_amdgcn_mfma_f32_16x16x32_bf16(af1, bf1, acc[1][1], 0, 0, 0);
    __syncthreads();
  }

#pragma unroll
  for (int r = 0; r < 2; ++r) {
#pragma unroll
    for (int c = 0; c < 2; ++c) {
      int col = n0 + wc*32 + c*16 + l15;
      if (col >= N) continue;
      int rowb = m0 + wr*32 + r*16 + (lane >> 4)*4;
#pragma unroll
      for (int j = 0; j < 4; ++j) {
        int row = rowb + j;
        if (row >= M) continue;
        atomicAdd(C + (size_t)row*ldc + col, acc[r][c][j]);
      }
    }
  }
}

// ---------------------------------------------------------------------------
// midk: per-chunk fused conv+SiLU -> xdbl GEMM -> delta -> local scan (p1).
// One block per 64-token chunk, 1024 threads. No atomics, no cross-block dep.
// Exports: uc (f32), xdbl (f32), dlt (f32), cP/cS.
// ---------------------------------------------------------------------------
union MidU {
  unsigned short Bs[48][392];                                   // 37.6 KB
  struct { float ds[64][64]; float us[64][64];
           float wdtS[64][12]; float bdtS[64]; } sc;            // 35.3 KB
};

__global__ __launch_bounds__(1024) void midk(
    const float* __restrict__ xz,
    const float* __restrict__ Wc, const float* __restrict__ bc,
    const float* __restrict__ Wx,
    const float* __restrict__ W_dt, const float* __restrict__ b_dt,
    const float* __restrict__ A_log,
    float* __restrict__ xdbl, float* __restrict__ uc,
    float* __restrict__ dlt, float* __restrict__ cP, float* __restrict__ cS) {
  __shared__ unsigned short Au[64][392];    // u bf16 [t][d]  49.2 KB
  __shared__ float xdblS[64][48];           // 12.3 KB
  __shared__ MidU U;
  int tid = threadIdx.x;
  int c = blockIdx.x;
  int t0 = c * CLEN;
  int nt = min(CLEN, L_TOK - t0);

  // --- conv + SiLU -> Au (bf16) + uc (f32 global) ---
  for (int i = tid; i < 64*DI; i += 1024) {
    int t = i / DI, d = i % DI;
    int tg = t0 + t;
    float u = 0.f;
    if (tg < L_TOK) {
      u = bc[d];
#pragma unroll
      for (int j = 0; j < 4; ++j) {
        int ts = tg - 3 + j;
        if (ts >= 0) u = fmaf(xz[(size_t)ts*(2*DI) + d], Wc[d*4 + j], u);
      }
      u = u / (1.0f + expf(-u));
      uc[(size_t)tg*DI + d] = u;
    }
    Au[t][d] = f2bf(u);
  }
  // --- stage Wx -> Bs bf16 (rows 44..47 zero) ---
  for (int i = tid; i < 48*DI; i += 1024) {
    int nr = i / DI, k = i % DI;
    U.Bs[nr][k] = (nr < XDBL_N) ? f2bf(Wx[(size_t)nr*DI + k]) : (unsigned short)0;
  }
  __syncthreads();

  // --- xdbl GEMM: 64x48 out, K=384; 12 waves each one 16x16 tile ---
  int wave = tid >> 6, lane = tid & 63;
  int l15 = lane & 15, lk = (lane >> 4) * 8;
  if (wave < 12) {
    int rt = wave / 3, ct = wave % 3;
    f32x4 acc = (f32x4){0.f,0.f,0.f,0.f};
#pragma unroll
    for (int kk = 0; kk < 12; ++kk) {
      short8 a = *(const short8*)&Au[rt*16 + l15][kk*32 + lk];
      short8 b = *(const short8*)&U.Bs[ct*16 + l15][kk*32 + lk];
      acc = __builtin_amdgcn_mfma_f32_16x16x32_bf16(a, b, acc, 0, 0, 0);
    }
    int colx = ct*16 + l15;
    int rowb = rt*16 + (lane >> 4)*4;
#pragma unroll
    for (int j = 0; j < 4; ++j) {
      int row = rowb + j;
      xdblS[row][colx] = acc[j];
      int tg = t0 + row;
      if (colx < XDBL_N && tg < L_TOK)
        xdbl[(size_t)tg*XDBL_N + colx] = acc[j];
    }
  }
  __syncthreads();

  // --- per-dgroup: delta + local scan; 6 groups of 64 channels ---
  int dq = tid >> 4, n = tid & 15;          // dq 0..63, n 0..15
  for (int dg = 0; dg < 6; ++dg) {
    int dbase = dg * 64;
    if (tid < 64*12)
      U.sc.wdtS[tid/12][tid%12] = W_dt[(size_t)(dbase + tid/12)*DTR + tid%12];
    if (tid < 64) U.sc.bdtS[tid] = b_dt[dbase + tid];
    for (int i = tid; i < 64*64; i += 1024) {
      int t = i >> 6, dd = i & 63;
      int tg = t0 + t;
      U.sc.us[t][dd] = (tg < L_TOK) ? uc[(size_t)tg*DI + dbase + dd] : 0.f;
    }
    __syncthreads();
    for (int i = tid; i < 64*64; i += 1024) {
      int t = i >> 6, dd = i & 63;
      float v = U.sc.bdtS[dd];
#pragma unroll
      for (int r = 0; r < 12; ++r)
        v = fmaf(xdblS[t][r], U.sc.wdtS[dd][r], v);
      v = (v > 20.0f) ? v : log1pf(expf(v));
      U.sc.ds[t][dd] = v;
      int tg = t0 + t;
      if (tg < L_TOK) dlt[(size_t)tg*DI + dbase + dd] = v;
    }
    __syncthreads();
    int d = dbase + dq;
    float a2 = -expf(A_log[d*DS + n]) * 1.44269504088896340736f;
    float s = 0.f, P = 1.f;
    for (int tt = 0; tt < nt; ++tt) {
      float dv = U.sc.ds[tt][dq];
      float dA = exp2f(dv * a2);
      s = fmaf(dA, s, dv * xdblS[tt][12 + n] * U.sc.us[tt][dq]);
      P *= dA;
    }
    int o = (c * DI + d) * DS + n;
    cP[o] = P;
    cS[o] = s;
    __syncthreads();
  }
}

// ---------------------------------------------------------------------------
// backk: per-chunk carry + emission (p3) + out-GEMM + residual (non-atomic).
// One block per chunk, 1024 threads.
// ---------------------------------------------------------------------------
union BackU {
  unsigned short Bs[64][392];                                   // 49.2 KB
  struct { float ds[64][64]; float us[64][64];
           float zs[64][64]; float xd[64][32]; } em;            // 56 KB
};

__global__ __launch_bounds__(1024) void backk(
    const float* __restrict__ uc, const float* __restrict__ dlt,
    const float* __restrict__ xdbl, const float* __restrict__ xz,
    const float* __restrict__ A_log, const float* __restrict__ Dp,
    const float* __restrict__ cP, const float* __restrict__ cS,
    const float* __restrict__ W_out, float* __restrict__ cur) {
  __shared__ unsigned short yS[64][392];    // y bf16 [t][d]  49.2 KB
  __shared__ BackU U;
  int tid = threadIdx.x;
  int c = blockIdx.x;
  int t0 = c * CLEN;
  int nt = min(CLEN, L_TOK - t0);
  int wave = tid >> 6, lane = tid & 63;
  int l15 = lane & 15, lk = (lane >> 4) * 8;
  int dq = tid >> 4, n = tid & 15;

  for (int i = tid; i < 64*392; i += 1024) ((unsigned short*)yS)[i] = 0;
  for (int i = tid; i < 64*32; i += 1024) {
    int t = i >> 5, q = i & 31;
    int tg = t0 + t;
    U.em.xd[t][q] = (tg < L_TOK) ? xdbl[(size_t)tg*XDBL_N + 12 + q] : 0.f;
  }

  // --- emission per dgroup ---
  for (int dg = 0; dg < 6; ++dg) {
    int dbase = dg * 64;
    for (int i = tid; i < 64*64; i += 1024) {
      int t = i >> 6, dd = i & 63;
      int tg = t0 + t;
      bool ok = (tg < L_TOK);
      U.em.us[t][dd] = ok ? uc[(size_t)tg*DI + dbase + dd] : 0.f;
      U.em.ds[t][dd] = ok ? dlt[(size_t)tg*DI + dbase + dd] : 0.f;
      U.em.zs[t][dd] = ok ? xz[(size_t)tg*(2*DI) + DI + dbase + dd] : 0.f;
    }
    __syncthreads();
    int d = dbase + dq;
    float a2 = -expf(A_log[d*DS + n]) * 1.44269504088896340736f;
    float dpv = Dp[d];
    float s = 0.f;
    {
      int oo = d * DS + n;
      for (int c2 = 0; c2 < c; ++c2)
        s = fmaf(cP[(size_t)c2*(DI*DS) + oo], s, cS[(size_t)c2*(DI*DS) + oo]);
    }
    for (int tt = 0; tt < nt; ++tt) {
      float dv = U.em.ds[tt][dq], uu = U.em.us[tt][dq];
      float dA = exp2f(dv * a2);
      s = fmaf(dA, s, dv * U.em.xd[tt][n] * uu);
      float p = s * U.em.xd[tt][16 + n];
      p += __shfl_xor(p, 1, 64);
      p += __shfl_xor(p, 2, 64);
      p += __shfl_xor(p, 4, 64);
      p += __shfl_xor(p, 8, 64);
      if (n == 0) {
        float z = U.em.zs[tt][dq];
        float y = fmaf(uu, dpv, p);
        y *= z / (1.0f + expf(-z));
        yS[tt][d] = f2bf(y);
      }
    }
    __syncthreads();
  }

  // --- out-GEMM: cur[t0..t0+63][0..192] += yS @ W_out^T, K=384 ---
  int rt = wave >> 2, ctw = wave & 3;       // 4x4 tiles over 64x64
  for (int n3 = 0; n3 < 3; ++n3) {
    __syncthreads();   // protect union switch / Bs reuse
    for (int i = tid; i < 64*DI; i += 1024) {
      int nr = i / DI, k = i % DI;
      U.Bs[nr][k] = f2bf(W_out[(size_t)(n3*64 + nr)*DI + k]);
    }
    __syncthreads();
    f32x4 acc = (f32x4){0.f,0.f,0.f,0.f};
#pragma unroll
    for (int kk = 0; kk < 12; ++kk) {
      short8 a = *(const short8*)&yS[rt*16 + l15][kk*32 + lk];
      short8 b = *(const short8*)&U.Bs[ctw*16 + l15][kk*32 + lk];
      acc = __builtin_amdgcn_mfma_f32_16x16x32_bf16(a, b, acc, 0, 0, 0);
    }
    int colx = n3*64 + ctw*16 + l15;
    int rowb = rt*16 + (lane >> 4)*4;
#pragma unroll
    for (int j = 0; j < 4; ++j) {
      int row = rowb + j;
      int tg = t0 + row;
      if (tg < L_TOK) cur[(size_t)tg*DM + colx] += acc[j];
    }
  }
}

// ---------------------------------------------------------------------------
extern "C" void kernel_launch(void* const* d_in, const int* in_sizes, int n_in,
                              void* d_out, int out_size, void* d_ws, size_t ws_size,
                              hipStream_t stream) {
  const float* x       = (const float*)d_in[0];
  const float* patch_w = (const float*)d_in[1];
  const float* patch_b = (const float*)d_in[2];
  const float* cls_tok = (const float*)d_in[3];
  const float* pos_emb = (const float*)d_in[4];
  const float* ln_g    = (const float*)d_in[5];
  const float* ln_b    = (const float*)d_in[6];
  const float* W_in    = (const float*)d_in[7];
  const float* Wc      = (const float*)d_in[8];
  const float* bc      = (const float*)d_in[9];
  const float* Wx      = (const float*)d_in[10];
  const float* W_dt    = (const float*)d_in[11];
  const float* b_dt    = (const float*)d_in[12];
  const float* A_log   = (const float*)d_in[13];
  const float* Dp      = (const float*)d_in[14];
  const float* W_out   = (const float*)d_in[15];
  const float* fn_g    = (const float*)d_in[16];
  const float* fn_b    = (const float*)d_in[17];

  float* ws = (float*)d_ws;
  float* cur   = ws;                       // 1569*192
  float* xz    = cur   + L_TOK*DM;         // 1569*768 (aliases px)
  float* xdbl  = xz    + L_TOK*2*DI;       // 1569*44
  float* uc    = xdbl  + L_TOK*XDBL_N;     // 1569*384
  float* dlt   = uc    + L_TOK*DI;         // 1569*384
  float* cP    = dlt   + L_TOK*DI;         // 25*6144
  float* cS    = cP    + NCHUNK*DI*DS;
  float* px    = xz;                       // im2col buffer, dead before layer-0 xz

  im2col_kernel<<<(NPATCH*192 + 255)/256, 256, 0, stream>>>(
      x, cls_tok, patch_b, pos_emb, px, cur);
  {
    dim3 grid(DM/64, (NPATCH + 63)/64, 4);
    mgemm_kernel<<<grid, 256, 0, stream>>>(px, 768, patch_w, 768, cur + DM, DM,
                                           NPATCH, DM, 768/4);
  }

  for (int dep = 0; dep < DEPTH; ++dep) {
    const float* g     = ln_g  + dep*DM;
    const float* bb    = ln_b  + dep*DM;
    const float* Win_l = W_in  + (size_t)dep*2*DI*DM;
    const float* Wc_l  = Wc    + (size_t)dep*DI*DCONV;
    const float* bc_l  = bc    + (size_t)dep*DI;
    const float* Wx_l  = Wx    + (size_t)dep*XDBL_N*DI;
    const float* Wdt_l = W_dt  + (size_t)dep*DI*DTR;
    const float* bdt_l = b_dt  + (size_t)dep*DI;
    const float* Alog_l= A_log + (size_t)dep*DI*DS;
    const float* Dp_l  = Dp    + (size_t)dep*DI;
    const float* Wout_l= W_out + (size_t)dep*DM*DI;

    // xz = LN(cur) @ W_in^T
    {
      dim3 grid((2*DI)/64, (L_TOK + 63)/64);
      lnxz_kernel<<<grid, 256, 0, stream>>>(cur, g, bb, Win_l, xz);
    }
    // conv+silu -> xdbl -> delta -> local scan (per-chunk)
    midk<<<NCHUNK, 1024, 0, stream>>>(xz, Wc_l, bc_l, Wx_l, Wdt_l, bdt_l,
                                      Alog_l, xdbl, uc, dlt, cP, cS);
    // carry + emission + out-GEMM + residual (per-chunk)
    backk<<<NCHUNK, 1024, 0, stream>>>(uc, dlt, xdbl, xz, Alog_l, Dp_l,
                                       cP, cS, Wout_l, cur);
  }

  ln_kernel<<<L_TOK, 64, 0, stream>>>(cur, (float*)d_out, fn_g, fn_b);
}

// Round 11
// 1492.627 us; speedup vs baseline: 1.6852x; 1.6852x over previous
//
#include <hip/hip_runtime.h>
#include <hip/hip_bf16.h>
#include <math.h>

#define L_TOK 1569
#define DM 192
#define DI 384
#define DS 16
#define DTR 12
#define DCONV 4
#define XDBL_N (DTR + 2*DS)   // 44
#define DEPTH 8
#define NCHUNK 25
#define CLEN 64
#define NPATCH 1568
#define NDG 24                // scan d-groups (384/16)

typedef __attribute__((ext_vector_type(8))) short short8;
typedef __attribute__((ext_vector_type(4))) float f32x4;

__device__ __forceinline__ unsigned short f2bf(float f) {
  unsigned int u = __float_as_uint(f);
  u += 0x7FFFu + ((u >> 16) & 1u);   // round-to-nearest-even
  return (unsigned short)(u >> 16);
}

__device__ __forceinline__ float bf2f(unsigned short h) {
  unsigned int u = ((unsigned int)h) << 16;
  return __uint_as_float(u);
}

// ---------------------------------------------------------------------------
// cur init: cur[tok][e] = pos[tok][e] + (tok==0 ? cls[e] : patch_b[e]).
// ---------------------------------------------------------------------------
__global__ __launch_bounds__(256) void init_kernel(
    const float* __restrict__ cls, const float* __restrict__ pb,
    const float* __restrict__ pos, float* __restrict__ curp) {
  int gid = blockIdx.x * 256 + threadIdx.x;
  const int initN = (L_TOK * DM) / 4;
  if (gid >= initN) return;
  int e4 = gid * 4;
  int tok = e4 / DM;
  int col = e4 % DM;
  float4 pv = *(const float4*)(pos + e4);
  float4 av = (tok == 0) ? *(const float4*)(cls + col)
                         : *(const float4*)(pb + col);
  float4 o = {pv.x + av.x, pv.y + av.y, pv.z + av.z, pv.w + av.w};
  *(float4*)(curp + e4) = o;
}

// ---------------------------------------------------------------------------
// Final LayerNorm. One wave per token.
// ---------------------------------------------------------------------------
__global__ __launch_bounds__(64) void ln_kernel(
    const float* __restrict__ in, float* __restrict__ out,
    const float* __restrict__ g, const float* __restrict__ b) {
  int tokn = blockIdx.x;
  int lane = threadIdx.x;
  const float* row = in + (size_t)tokn*DM;
  float x0 = row[lane], x1 = row[lane+64], x2 = row[lane+128];
  float s = x0 + x1 + x2;
  float s2 = x0*x0 + x1*x1 + x2*x2;
#pragma unroll
  for (int off = 1; off < 64; off <<= 1) {
    s  += __shfl_xor(s,  off, 64);
    s2 += __shfl_xor(s2, off, 64);
  }
  float m = s * (1.0f/192.0f);
  float v = s2 * (1.0f/192.0f) - m*m;
  float rs = rsqrtf(v + 1e-5f);
  float* orow = out + (size_t)tokn*DM;
  orow[lane]     = (x0 - m)*rs*g[lane]     + b[lane];
  orow[lane+64]  = (x1 - m)*rs*g[lane+64]  + b[lane+64];
  orow[lane+128] = (x2 - m)*rs*g[lane+128] + b[lane+128];
}

// ---------------------------------------------------------------------------
// Patch GEMM, im2col fused into A-staging: cur[1..][:] += X_patch @ patch_w^T.
// M=1568, N=192, K=768, split-K 4 (ksl=192), atomicAdd (cur pre-init).
// ---------------------------------------------------------------------------
__device__ __forceinline__ float4 ldx4(const float* __restrict__ x,
                                       int pt, int hh, int w, int k) {
  int c = k >> 8, p = (k >> 4) & 15, q = k & 15;
  return *(const float4*)(x + ((size_t)(c*8 + pt)*224 + hh*16 + p)*224
                            + w*16 + q);
}

__global__ __launch_bounds__(256) void patch_gemm(
    const float* __restrict__ x, const float* __restrict__ pw,
    float* __restrict__ C) {
  __shared__ unsigned short As[64*40];
  __shared__ unsigned short Bs[64*40];
  int tid = threadIdx.x;
  int m0 = blockIdx.y * 64, n0 = blockIdx.x * 64;
  int kbase = blockIdx.z * 192;
  int wave = tid >> 6, lane = tid & 63;
  int wr = wave >> 1, wc = wave & 1;
  int srow = tid >> 2;
  int skq  = (tid & 3) * 8;
  f32x4 acc[2][2];
#pragma unroll
  for (int i = 0; i < 2; ++i)
#pragma unroll
    for (int j = 0; j < 2; ++j) acc[i][j] = (f32x4){0.f,0.f,0.f,0.f};

  int am = m0 + srow;
  bool a_ok = (am < NPATCH);
  int am_s = a_ok ? am : 0;
  int pt = am_s / 196, hw = am_s % 196, hh = hw / 14, w = hw % 14;
  int bn = n0 + srow;
  const float* bp = pw + (size_t)bn*768 + kbase + skq;
  const float4 z4 = {0.f,0.f,0.f,0.f};
  int l15 = lane & 15, lk = (lane >> 4) * 8;

  const int nt = 6;   // 192/32
  float4 a0 = a_ok ? ldx4(x, pt, hh, w, kbase + skq)     : z4;
  float4 a1 = a_ok ? ldx4(x, pt, hh, w, kbase + skq + 4) : z4;
  float4 b0 = *(const float4*)(bp);
  float4 b1 = *(const float4*)(bp + 4);

  for (int i = 0; i < nt; ++i) {
    {
      short8 pa, pb;
      pa[0]=f2bf(a0.x); pa[1]=f2bf(a0.y); pa[2]=f2bf(a0.z); pa[3]=f2bf(a0.w);
      pa[4]=f2bf(a1.x); pa[5]=f2bf(a1.y); pa[6]=f2bf(a1.z); pa[7]=f2bf(a1.w);
      pb[0]=f2bf(b0.x); pb[1]=f2bf(b0.y); pb[2]=f2bf(b0.z); pb[3]=f2bf(b0.w);
      pb[4]=f2bf(b1.x); pb[5]=f2bf(b1.y); pb[6]=f2bf(b1.z); pb[7]=f2bf(b1.w);
      *(short8*)&As[srow*40 + skq] = pa;
      *(short8*)&Bs[srow*40 + skq] = pb;
    }
    __syncthreads();
    bool pf = (i + 1 < nt);
    int kn = kbase + ((i + 1) << 5) + skq;
    a0 = (pf && a_ok) ? ldx4(x, pt, hh, w, kn)     : z4;
    a1 = (pf && a_ok) ? ldx4(x, pt, hh, w, kn + 4) : z4;
    b0 = pf ? *(const float4*)(bp + ((i+1)<<5))     : z4;
    b1 = pf ? *(const float4*)(bp + ((i+1)<<5) + 4) : z4;

    short8 af0 = *(const short8*)&As[(wr*32      + l15)*40 + lk];
    short8 af1 = *(const short8*)&As[(wr*32 + 16 + l15)*40 + lk];
    short8 bf0 = *(const short8*)&Bs[(wc*32      + l15)*40 + lk];
    short8 bf1 = *(const short8*)&Bs[(wc*32 + 16 + l15)*40 + lk];
    acc[0][0] = __builtin_amdgcn_mfma_f32_16x16x32_bf16(af0, bf0, acc[0][0], 0, 0, 0);
    acc[0][1] = __builtin_amdgcn_mfma_f32_16x16x32_bf16(af0, bf1, acc[0][1], 0, 0, 0);
    acc[1][0] = __builtin_amdgcn_mfma_f32_16x16x32_bf16(af1, bf0, acc[1][0], 0, 0, 0);
    acc[1][1] = __builtin_amdgcn_mfma_f32_16x16x32_bf16(af1, bf1, acc[1][1], 0, 0, 0);
    __syncthreads();
  }

#pragma unroll
  for (int r = 0; r < 2; ++r) {
#pragma unroll
    for (int c = 0; c < 2; ++c) {
      int col = n0 + wc*32 + c*16 + l15;
      int rowb = m0 + wr*32 + r*16 + (lane >> 4)*4;
#pragma unroll
      for (int j = 0; j < 4; ++j) {
        int row = rowb + j;
        if (row < NPATCH)
          atomicAdd(C + (size_t)row*DM + col, acc[r][c][j]);
      }
    }
  }
}

// ---------------------------------------------------------------------------
// Fused LN + xz GEMM (K=192 fully in LDS, one barrier before 6 MFMA k-steps).
// ---------------------------------------------------------------------------
__global__ __launch_bounds__(256) void lnxz_kernel(
    const float* __restrict__ cur, const float* __restrict__ g,
    const float* __restrict__ b, const float* __restrict__ W,
    float* __restrict__ xz) {
  __shared__ unsigned short As[64][200];
  __shared__ unsigned short Bs[64][200];
  __shared__ float gs[192], bs2[192];
  int tid = threadIdx.x;
  int m0 = blockIdx.y * 64, n0 = blockIdx.x * 64;
  int wave = tid >> 6, lane = tid & 63;
  int wr = wave >> 1, wc = wave & 1;
  int l15 = lane & 15, lk = (lane >> 4) * 8;

  for (int i = tid; i < 192; i += 256) { gs[i] = g[i]; bs2[i] = b[i]; }

  int r = tid >> 2, c0 = (tid & 3) * 48;
  float v[48];
  {
    int row = m0 + r;
    if (row < L_TOK) {
      const float* rp = cur + (size_t)row*DM + c0;
#pragma unroll
      for (int j = 0; j < 12; ++j) {
        float4 t4 = *(const float4*)(rp + j*4);
        v[j*4+0]=t4.x; v[j*4+1]=t4.y; v[j*4+2]=t4.z; v[j*4+3]=t4.w;
      }
    } else {
#pragma unroll
      for (int j = 0; j < 48; ++j) v[j] = 0.f;
    }
  }
  float s = 0.f, s2 = 0.f;
#pragma unroll
  for (int j = 0; j < 48; ++j) { s += v[j]; s2 += v[j]*v[j]; }
  s  += __shfl_xor(s, 1, 64); s2 += __shfl_xor(s2, 1, 64);
  s  += __shfl_xor(s, 2, 64); s2 += __shfl_xor(s2, 2, 64);
  float mu = s * (1.0f/192.0f);
  float var = s2 * (1.0f/192.0f) - mu*mu;
  float rsd = rsqrtf(var + 1e-5f);

  __syncthreads();
#pragma unroll
  for (int j = 0; j < 48; ++j) {
    int k = c0 + j;
    As[r][k] = f2bf((v[j] - mu)*rsd*gs[k] + bs2[k]);
  }
  {
    const float* rp = W + (size_t)(n0 + r)*DM + c0;
#pragma unroll
    for (int j = 0; j < 12; ++j) {
      float4 t4 = *(const float4*)(rp + j*4);
      Bs[r][c0+j*4+0]=f2bf(t4.x); Bs[r][c0+j*4+1]=f2bf(t4.y);
      Bs[r][c0+j*4+2]=f2bf(t4.z); Bs[r][c0+j*4+3]=f2bf(t4.w);
    }
  }
  __syncthreads();

  f32x4 acc[2][2];
#pragma unroll
  for (int i = 0; i < 2; ++i)
#pragma unroll
    for (int j = 0; j < 2; ++j) acc[i][j] = (f32x4){0.f,0.f,0.f,0.f};

#pragma unroll
  for (int kk = 0; kk < 6; ++kk) {
    short8 af0 = *(const short8*)&As[wr*32      + l15][kk*32 + lk];
    short8 af1 = *(const short8*)&As[wr*32 + 16 + l15][kk*32 + lk];
    short8 bf0 = *(const short8*)&Bs[wc*32      + l15][kk*32 + lk];
    short8 bf1 = *(const short8*)&Bs[wc*32 + 16 + l15][kk*32 + lk];
    acc[0][0] = __builtin_amdgcn_mfma_f32_16x16x32_bf16(af0, bf0, acc[0][0], 0, 0, 0);
    acc[0][1] = __builtin_amdgcn_mfma_f32_16x16x32_bf16(af0, bf1, acc[0][1], 0, 0, 0);
    acc[1][0] = __builtin_amdgcn_mfma_f32_16x16x32_bf16(af1, bf0, acc[1][0], 0, 0, 0);
    acc[1][1] = __builtin_amdgcn_mfma_f32_16x16x32_bf16(af1, bf1, acc[1][1], 0, 0, 0);
  }

#pragma unroll
  for (int rr = 0; rr < 2; ++rr) {
#pragma unroll
    for (int cc = 0; cc < 2; ++cc) {
      int col = n0 + wc*32 + cc*16 + l15;
      int rowb = m0 + wr*32 + rr*16 + (lane >> 4)*4;
#pragma unroll
      for (int j = 0; j < 4; ++j) {
        int row = rowb + j;
        if (row < L_TOK) xz[(size_t)row*(2*DI) + col] = acc[rr][cc][j];
      }
    }
  }
}

// ---------------------------------------------------------------------------
// midk: conv+SiLU -> xdbl GEMM (64x48, K=384, sequential) -> delta -> local
// scan (p1) for 4 dgroups. grid (6, 25) = 150 blocks, 256 thr, ~71 KB LDS.
// g==0 blocks export uc (f32) and xdbl[12:44]; every block exports its
// dlt slice and cP/cS slices. No atomics anywhere.
// ---------------------------------------------------------------------------
__global__ __launch_bounds__(256) void midk(
    const float* __restrict__ xz,
    const float* __restrict__ Wc, const float* __restrict__ bc,
    const float* __restrict__ Wx,
    const float* __restrict__ W_dt, const float* __restrict__ b_dt,
    const float* __restrict__ A_log,
    float* __restrict__ xdbl, float* __restrict__ uc,
    float* __restrict__ dlt, float* __restrict__ cP, float* __restrict__ cS) {
  __shared__ unsigned short Au[64][392];   // u bf16, 50176 B
  __shared__ unsigned short Ws[48][40];    // Wx k-slice bf16, 3840 B
  __shared__ float xdblS[64][48];          // 12288 B
  __shared__ float dsS[64][16];            // 4096 B
  __shared__ float wdtS[16][12];           // 768 B
  __shared__ float bdsS[16];
  int tid = threadIdx.x;
  int g = blockIdx.x;            // 0..5 (64-channel group)
  int c = blockIdx.y;            // chunk
  int t0 = c * CLEN;
  int wave = tid >> 6, lane = tid & 63;
  int l15 = lane & 15, lk = (lane >> 4) * 8;

  // --- conv + SiLU for all 384 channels (padded rows -> 0) ---
  for (int i = tid; i < CLEN*DI; i += 256) {
    int t = i / DI, d = i % DI;
    int tg = t0 + t;
    float u = 0.f;
    if (tg < L_TOK) {
      u = bc[d];
#pragma unroll
      for (int j = 0; j < 4; ++j) {
        int ts = tg - 3 + j;
        if (ts >= 0) u = fmaf(xz[(size_t)ts*(2*DI) + d], Wc[d*4 + j], u);
      }
      u = u / (1.0f + expf(-u));
      if (g == 0) uc[(size_t)tg*DI + d] = u;
    }
    Au[t][d] = f2bf(u);
  }
  __syncthreads();

  // --- xdbl GEMM: 64x48 = Au @ [Wx;0]^T, K=384, 12 k-steps ---
  f32x4 acc[3];
#pragma unroll
  for (int q = 0; q < 3; ++q) acc[q] = (f32x4){0.f,0.f,0.f,0.f};
  for (int i = 0; i < 12; ++i) {
    for (int idx = tid; idx < 48*32; idx += 256) {
      int nr = idx >> 5, kk = idx & 31;
      float v = (nr < XDBL_N) ? Wx[(size_t)nr*DI + i*32 + kk] : 0.f;
      Ws[nr][kk] = f2bf(v);
    }
    __syncthreads();
#pragma unroll
    for (int q = 0; q < 3; ++q) {
      short8 a = *(const short8*)&Au[wave*16 + l15][i*32 + lk];
      short8 b = *(const short8*)&Ws[q*16 + l15][lk];
      acc[q] = __builtin_amdgcn_mfma_f32_16x16x32_bf16(a, b, acc[q], 0, 0, 0);
    }
    __syncthreads();
  }
#pragma unroll
  for (int q = 0; q < 3; ++q) {
    int colx = q*16 + l15;
    int rowb = wave*16 + (lane >> 4)*4;
#pragma unroll
    for (int j = 0; j < 4; ++j) {
      int row = rowb + j;
      xdblS[row][colx] = acc[q][j];
      int tg = t0 + row;
      if (g == 0 && colx >= 12 && colx < XDBL_N && tg < L_TOK)
        xdbl[(size_t)tg*XDBL_N + colx] = acc[q][j];
    }
  }
  __syncthreads();

  // --- 4 rounds: delta + local scan for dgroups 4g..4g+3 ---
  int dl = tid >> 4, n = tid & 15;
  for (int rr = 0; rr < 4; ++rr) {
    int dbase = g*64 + rr*16;
    if (tid < 192) wdtS[tid/12][tid%12] = W_dt[(size_t)(dbase + tid/12)*DTR + tid%12];
    if (tid < 16)  bdsS[tid] = b_dt[dbase + tid];
    __syncthreads();
    for (int i = tid; i < CLEN*16; i += 256) {
      int t = i >> 4, dd = i & 15;
      float v = bdsS[dd];
#pragma unroll
      for (int r2 = 0; r2 < 12; ++r2)
        v = fmaf(xdblS[t][r2], wdtS[dd][r2], v);
      v = (v > 20.0f) ? v : log1pf(expf(v));
      dsS[t][dd] = v;
      int tg = t0 + t;
      if (tg < L_TOK) dlt[(size_t)tg*DI + dbase + dd] = v;
    }
    __syncthreads();
    int d = dbase + dl;
    float a2 = -expf(A_log[d*DS + n]) * 1.44269504088896340736f;
    float s = 0.f, P = 1.f;
#pragma unroll 4
    for (int tt = 0; tt < CLEN; ++tt) {
      float dv = dsS[tt][dl];
      float dA = exp2f(dv * a2);
      s = fmaf(dA, s, dv * xdblS[tt][12 + n] * bf2f(Au[tt][d]));
      P *= dA;
    }
    int o = (c * DI + d) * DS + n;
    cP[o] = P;
    cS[o] = s;
    __syncthreads();
  }
}

// ---------------------------------------------------------------------------
// scan_p3: carry-in combine over preceding chunks, re-scan, emit y.
// grid (NDG, NCHUNK) = 600 blocks, 256 thr.
// ---------------------------------------------------------------------------
__global__ __launch_bounds__(256) void scan_p3(
    const float* __restrict__ uc, const float* __restrict__ dlt,
    const float* __restrict__ xdbl, const float* __restrict__ xz,
    const float* __restrict__ A_log, const float* __restrict__ Dp,
    const float* __restrict__ cP, const float* __restrict__ cS,
    float* __restrict__ yy) {
  __shared__ float us[CLEN][16], ds[CLEN][16], bs[CLEN][16];
  __shared__ float cs[CLEN][16], zs[CLEN][16];
  int tid = threadIdx.x;
  int dl = tid >> 4, n = tid & 15;
  int d0 = blockIdx.x * 16;
  int cidx = blockIdx.y;
  int t0 = cidx * CLEN;
  int nt = min(CLEN, L_TOK - t0);
  int d = d0 + dl;

  float s = 0.0f;
  {
    int oo = d * DS + n;
    for (int c2 = 0; c2 < cidx; ++c2)
      s = fmaf(cP[(size_t)c2*(DI*DS) + oo], s, cS[(size_t)c2*(DI*DS) + oo]);
  }

  for (int i = tid; i < CLEN*16; i += 256) {
    int tt = i >> 4, dd = i & 15;
    int t = t0 + tt;
    bool ok = (t < L_TOK);
    us[tt][dd] = ok ? uc[(size_t)t*DI + d0 + dd] : 0.f;
    ds[tt][dd] = ok ? dlt[(size_t)t*DI + d0 + dd] : 0.f;
    zs[tt][dd] = ok ? xz[(size_t)t*(2*DI) + DI + d0 + dd] : 0.f;
  }
  for (int i = tid; i < CLEN*32; i += 256) {
    int tt = i >> 5, cq = i & 31;
    int t = t0 + tt;
    float v = (t < L_TOK) ? xdbl[(size_t)t*XDBL_N + 12 + cq] : 0.f;
    if (cq < 16) bs[tt][cq] = v;
    else cs[tt][cq-16] = v;
  }
  __syncthreads();

  float a2 = -expf(A_log[d*DS + n]) * 1.44269504088896340736f;
  float dpv = Dp[d];
#pragma unroll 4
  for (int tt = 0; tt < CLEN; ++tt) {
    float dv = ds[tt][dl], uu = us[tt][dl];
    float dA = exp2f(dv * a2);
    s = fmaf(dA, s, dv * bs[tt][n] * uu);
    float p = s * cs[tt][n];
    p += __shfl_xor(p, 1, 64);
    p += __shfl_xor(p, 2, 64);
    p += __shfl_xor(p, 4, 64);
    p += __shfl_xor(p, 8, 64);
    if (n == 0 && tt < nt) {
      float z = zs[tt][dl];
      float y = fmaf(uu, dpv, p);
      y *= z / (1.0f + expf(-z));
      yy[(size_t)(t0 + tt)*DI + d] = y;
    }
  }
}

// ---------------------------------------------------------------------------
// out projection: cur += yy @ W_out^T, M=1569, N=192, K=384, split-K 4,
// atomicAdd residual into cur.
// ---------------------------------------------------------------------------
__global__ __launch_bounds__(256) void mgemm_kernel(
    const float* __restrict__ A, int lda,
    const float* __restrict__ B, int ldb,
    float* __restrict__ C, int ldc,
    int M, int N, int ksl) {
  __shared__ unsigned short As[64*40];
  __shared__ unsigned short Bs[64*40];
  int tid = threadIdx.x;
  int m0 = blockIdx.y * 64, n0 = blockIdx.x * 64;
  int kbase = blockIdx.z * ksl;
  int wave = tid >> 6, lane = tid & 63;
  int wr = wave >> 1, wc = wave & 1;
  int srow = tid >> 2;
  int skq  = (tid & 3) * 8;
  f32x4 acc[2][2];
#pragma unroll
  for (int i = 0; i < 2; ++i)
#pragma unroll
    for (int j = 0; j < 2; ++j) acc[i][j] = (f32x4){0.f,0.f,0.f,0.f};

  int am = m0 + srow;
  int bn = n0 + srow;
  bool a_ok = (am < M), b_ok = (bn < N);
  const float* ap = A + (size_t)am*lda + kbase + skq;
  const float* bp = B + (size_t)bn*ldb + kbase + skq;
  const float4 z4 = {0.f,0.f,0.f,0.f};
  int l15 = lane & 15, lk = (lane >> 4) * 8;

  int nt = ksl >> 5;
  float4 a0 = a_ok ? *(const float4*)(ap)     : z4;
  float4 a1 = a_ok ? *(const float4*)(ap + 4) : z4;
  float4 b0 = b_ok ? *(const float4*)(bp)     : z4;
  float4 b1 = b_ok ? *(const float4*)(bp + 4) : z4;

  for (int i = 0; i < nt; ++i) {
    {
      short8 pa, pb;
      pa[0]=f2bf(a0.x); pa[1]=f2bf(a0.y); pa[2]=f2bf(a0.z); pa[3]=f2bf(a0.w);
      pa[4]=f2bf(a1.x); pa[5]=f2bf(a1.y); pa[6]=f2bf(a1.z); pa[7]=f2bf(a1.w);
      pb[0]=f2bf(b0.x); pb[1]=f2bf(b0.y); pb[2]=f2bf(b0.z); pb[3]=f2bf(b0.w);
      pb[4]=f2bf(b1.x); pb[5]=f2bf(b1.y); pb[6]=f2bf(b1.z); pb[7]=f2bf(b1.w);
      *(short8*)&As[srow*40 + skq] = pa;
      *(short8*)&Bs[srow*40 + skq] = pb;
    }
    __syncthreads();
    bool pf = (i + 1 < nt);
    int k0n = (i + 1) << 5;
    a0 = (pf && a_ok) ? *(const float4*)(ap + k0n)     : z4;
    a1 = (pf && a_ok) ? *(const float4*)(ap + k0n + 4) : z4;
    b0 = (pf && b_ok) ? *(const float4*)(bp + k0n)     : z4;
    b1 = (pf && b_ok) ? *(const float4*)(bp + k0n + 4) : z4;

    short8 af0 = *(const short8*)&As[(wr*32      + l15)*40 + lk];
    short8 af1 = *(const short8*)&As[(wr*32 + 16 + l15)*40 + lk];
    short8 bf0 = *(const short8*)&Bs[(wc*32      + l15)*40 + lk];
    short8 bf1 = *(const short8*)&Bs[(wc*32 + 16 + l15)*40 + lk];
    acc[0][0] = __builtin_amdgcn_mfma_f32_16x16x32_bf16(af0, bf0, acc[0][0], 0, 0, 0);
    acc[0][1] = __builtin_amdgcn_mfma_f32_16x16x32_bf16(af0, bf1, acc[0][1], 0, 0, 0);
    acc[1][0] = __builtin_amdgcn_mfma_f32_16x16x32_bf16(af1, bf0, acc[1][0], 0, 0, 0);
    acc[1][1] = __builtin_amdgcn_mfma_f32_16x16x32_bf16(af1, bf1, acc[1][1], 0, 0, 0);
    __syncthreads();
  }

#pragma unroll
  for (int r = 0; r < 2; ++r) {
#pragma unroll
    for (int c = 0; c < 2; ++c) {
      int col = n0 + wc*32 + c*16 + l15;
      if (col >= N) continue;
      int rowb = m0 + wr*32 + r*16 + (lane >> 4)*4;
#pragma unroll
      for (int j = 0; j < 4; ++j) {
        int row = rowb + j;
        if (row >= M) continue;
        atomicAdd(C + (size_t)row*ldc + col, acc[r][c][j]);
      }
    }
  }
}

// ---------------------------------------------------------------------------
extern "C" void kernel_launch(void* const* d_in, const int* in_sizes, int n_in,
                              void* d_out, int out_size, void* d_ws, size_t ws_size,
                              hipStream_t stream) {
  const float* x       = (const float*)d_in[0];
  const float* patch_w = (const float*)d_in[1];
  const float* patch_b = (const float*)d_in[2];
  const float* cls_tok = (const float*)d_in[3];
  const float* pos_emb = (const float*)d_in[4];
  const float* ln_g    = (const float*)d_in[5];
  const float* ln_b    = (const float*)d_in[6];
  const float* W_in    = (const float*)d_in[7];
  const float* Wc      = (const float*)d_in[8];
  const float* bc      = (const float*)d_in[9];
  const float* Wx      = (const float*)d_in[10];
  const float* W_dt    = (const float*)d_in[11];
  const float* b_dt    = (const float*)d_in[12];
  const float* A_log   = (const float*)d_in[13];
  const float* Dp      = (const float*)d_in[14];
  const float* W_out   = (const float*)d_in[15];
  const float* fn_g    = (const float*)d_in[16];
  const float* fn_b    = (const float*)d_in[17];

  float* ws = (float*)d_ws;
  float* cur   = ws;                       // 1569*192
  float* xz    = cur   + L_TOK*DM;         // 1569*768
  float* xdbl  = xz    + L_TOK*2*DI;       // 1569*44
  float* uc    = xdbl  + L_TOK*XDBL_N;     // 1569*384
  float* dlt   = uc    + L_TOK*DI;         // 1569*384
  float* yy    = dlt   + L_TOK*DI;         // 1569*384
  float* cP    = yy    + L_TOK*DI;         // 25*6144
  float* cS    = cP    + NCHUNK*DI*DS;

  init_kernel<<<(L_TOK*DM/4 + 255)/256, 256, 0, stream>>>(
      cls_tok, patch_b, pos_emb, cur);
  {
    dim3 grid(DM/64, (NPATCH + 63)/64, 4);
    patch_gemm<<<grid, 256, 0, stream>>>(x, patch_w, cur + DM);
  }

  for (int dep = 0; dep < DEPTH; ++dep) {
    const float* g     = ln_g  + dep*DM;
    const float* bb    = ln_b  + dep*DM;
    const float* Win_l = W_in  + (size_t)dep*2*DI*DM;
    const float* Wc_l  = Wc    + (size_t)dep*DI*DCONV;
    const float* bc_l  = bc    + (size_t)dep*DI;
    const float* Wx_l  = Wx    + (size_t)dep*XDBL_N*DI;
    const float* Wdt_l = W_dt  + (size_t)dep*DI*DTR;
    const float* bdt_l = b_dt  + (size_t)dep*DI;
    const float* Alog_l= A_log + (size_t)dep*DI*DS;
    const float* Dp_l  = Dp    + (size_t)dep*DI;
    const float* Wout_l= W_out + (size_t)dep*DM*DI;

    // xz = LN(cur) @ W_in^T
    {
      dim3 grid((2*DI)/64, (L_TOK + 63)/64);
      lnxz_kernel<<<grid, 256, 0, stream>>>(cur, g, bb, Win_l, xz);
    }
    // conv+silu -> xdbl -> delta -> local scan (merged cgemm+p1)
    {
      dim3 grid(6, NCHUNK);
      midk<<<grid, 256, 0, stream>>>(xz, Wc_l, bc_l, Wx_l, Wdt_l, bdt_l,
                                     Alog_l, xdbl, uc, dlt, cP, cS);
    }
    // carry + emission
    {
      dim3 grid(NDG, NCHUNK);
      scan_p3<<<grid, 256, 0, stream>>>(uc, dlt, xdbl, xz, Alog_l, Dp_l,
                                        cP, cS, yy);
    }
    // cur += yy @ W_out^T
    {
      dim3 grid(DM/64, (L_TOK + 63)/64, 4);
      mgemm_kernel<<<grid, 256, 0, stream>>>(yy, DI, Wout_l, DI, cur, DM,
                                             L_TOK, DM, DI/4);
    }
  }

  ln_kernel<<<L_TOK, 64, 0, stream>>>(cur, (float*)d_out, fn_g, fn_b);
}

// Round 12
// 586.858 us; speedup vs baseline: 4.2861x; 2.5434x over previous
//
#include <hip/hip_runtime.h>
#include <hip/hip_bf16.h>
#include <math.h>

#define L_TOK 1569
#define DM 192
#define DI 384
#define DS 16
#define DTR 12
#define DCONV 4
#define XDBL_N (DTR + 2*DS)   // 44
#define DEPTH 8
#define NCHUNK 50
#define CLEN 32
#define NPATCH 1568
#define NDG 24                // scan d-groups (384/16)

typedef __attribute__((ext_vector_type(8))) short short8;
typedef __attribute__((ext_vector_type(4))) float f32x4;

__device__ __forceinline__ unsigned short f2bf(float f) {
  unsigned int u = __float_as_uint(f);
  u += 0x7FFFu + ((u >> 16) & 1u);   // round-to-nearest-even
  return (unsigned short)(u >> 16);
}

// ---------------------------------------------------------------------------
// cur init: cur[tok][e] = pos[tok][e] + (tok==0 ? cls[e] : patch_b[e]).
// ---------------------------------------------------------------------------
__global__ __launch_bounds__(256) void init_kernel(
    const float* __restrict__ cls, const float* __restrict__ pb,
    const float* __restrict__ pos, float* __restrict__ curp) {
  int gid = blockIdx.x * 256 + threadIdx.x;
  const int initN = (L_TOK * DM) / 4;
  if (gid >= initN) return;
  int e4 = gid * 4;
  int tok = e4 / DM;
  int col = e4 % DM;
  float4 pv = *(const float4*)(pos + e4);
  float4 av = (tok == 0) ? *(const float4*)(cls + col)
                         : *(const float4*)(pb + col);
  float4 o = {pv.x + av.x, pv.y + av.y, pv.z + av.z, pv.w + av.w};
  *(float4*)(curp + e4) = o;
}

// ---------------------------------------------------------------------------
// Final LayerNorm. One wave per token.
// ---------------------------------------------------------------------------
__global__ __launch_bounds__(64) void ln_kernel(
    const float* __restrict__ in, float* __restrict__ out,
    const float* __restrict__ g, const float* __restrict__ b) {
  int tokn = blockIdx.x;
  int lane = threadIdx.x;
  const float* row = in + (size_t)tokn*DM;
  float x0 = row[lane], x1 = row[lane+64], x2 = row[lane+128];
  float s = x0 + x1 + x2;
  float s2 = x0*x0 + x1*x1 + x2*x2;
#pragma unroll
  for (int off = 1; off < 64; off <<= 1) {
    s  += __shfl_xor(s,  off, 64);
    s2 += __shfl_xor(s2, off, 64);
  }
  float m = s * (1.0f/192.0f);
  float v = s2 * (1.0f/192.0f) - m*m;
  float rs = rsqrtf(v + 1e-5f);
  float* orow = out + (size_t)tokn*DM;
  orow[lane]     = (x0 - m)*rs*g[lane]     + b[lane];
  orow[lane+64]  = (x1 - m)*rs*g[lane+64]  + b[lane+64];
  orow[lane+128] = (x2 - m)*rs*g[lane+128] + b[lane+128];
}

// ---------------------------------------------------------------------------
// Patch GEMM, im2col fused into A-staging: cur[1..][:] += X_patch @ patch_w^T.
// M=1568, N=192, K=768, split-K 4 (ksl=192), atomicAdd (cur pre-init).
// ---------------------------------------------------------------------------
__device__ __forceinline__ float4 ldx4(const float* __restrict__ x,
                                       int pt, int hh, int w, int k) {
  int c = k >> 8, p = (k >> 4) & 15, q = k & 15;
  return *(const float4*)(x + ((size_t)(c*8 + pt)*224 + hh*16 + p)*224
                            + w*16 + q);
}

__global__ __launch_bounds__(256) void patch_gemm(
    const float* __restrict__ x, const float* __restrict__ pw,
    float* __restrict__ C) {
  __shared__ unsigned short As[64*40];
  __shared__ unsigned short Bs[64*40];
  int tid = threadIdx.x;
  int m0 = blockIdx.y * 64, n0 = blockIdx.x * 64;
  int kbase = blockIdx.z * 192;
  int wave = tid >> 6, lane = tid & 63;
  int wr = wave >> 1, wc = wave & 1;
  int srow = tid >> 2;
  int skq  = (tid & 3) * 8;
  f32x4 acc[2][2];
#pragma unroll
  for (int i = 0; i < 2; ++i)
#pragma unroll
    for (int j = 0; j < 2; ++j) acc[i][j] = (f32x4){0.f,0.f,0.f,0.f};

  int am = m0 + srow;
  bool a_ok = (am < NPATCH);
  int am_s = a_ok ? am : 0;
  int pt = am_s / 196, hw = am_s % 196, hh = hw / 14, w = hw % 14;
  int bn = n0 + srow;
  const float* bp = pw + (size_t)bn*768 + kbase + skq;
  const float4 z4 = {0.f,0.f,0.f,0.f};
  int l15 = lane & 15, lk = (lane >> 4) * 8;

  const int nt = 6;   // 192/32
  float4 a0 = a_ok ? ldx4(x, pt, hh, w, kbase + skq)     : z4;
  float4 a1 = a_ok ? ldx4(x, pt, hh, w, kbase + skq + 4) : z4;
  float4 b0 = *(const float4*)(bp);
  float4 b1 = *(const float4*)(bp + 4);

  for (int i = 0; i < nt; ++i) {
    {
      short8 pa, pb;
      pa[0]=f2bf(a0.x); pa[1]=f2bf(a0.y); pa[2]=f2bf(a0.z); pa[3]=f2bf(a0.w);
      pa[4]=f2bf(a1.x); pa[5]=f2bf(a1.y); pa[6]=f2bf(a1.z); pa[7]=f2bf(a1.w);
      pb[0]=f2bf(b0.x); pb[1]=f2bf(b0.y); pb[2]=f2bf(b0.z); pb[3]=f2bf(b0.w);
      pb[4]=f2bf(b1.x); pb[5]=f2bf(b1.y); pb[6]=f2bf(b1.z); pb[7]=f2bf(b1.w);
      *(short8*)&As[srow*40 + skq] = pa;
      *(short8*)&Bs[srow*40 + skq] = pb;
    }
    __syncthreads();
    bool pf = (i + 1 < nt);
    int kn = kbase + ((i + 1) << 5) + skq;
    a0 = (pf && a_ok) ? ldx4(x, pt, hh, w, kn)     : z4;
    a1 = (pf && a_ok) ? ldx4(x, pt, hh, w, kn + 4) : z4;
    b0 = pf ? *(const float4*)(bp + ((i+1)<<5))     : z4;
    b1 = pf ? *(const float4*)(bp + ((i+1)<<5) + 4) : z4;

    short8 af0 = *(const short8*)&As[(wr*32      + l15)*40 + lk];
    short8 af1 = *(const short8*)&As[(wr*32 + 16 + l15)*40 + lk];
    short8 bf0 = *(const short8*)&Bs[(wc*32      + l15)*40 + lk];
    short8 bf1 = *(const short8*)&Bs[(wc*32 + 16 + l15)*40 + lk];
    acc[0][0] = __builtin_amdgcn_mfma_f32_16x16x32_bf16(af0, bf0, acc[0][0], 0, 0, 0);
    acc[0][1] = __builtin_amdgcn_mfma_f32_16x16x32_bf16(af0, bf1, acc[0][1], 0, 0, 0);
    acc[1][0] = __builtin_amdgcn_mfma_f32_16x16x32_bf16(af1, bf0, acc[1][0], 0, 0, 0);
    acc[1][1] = __builtin_amdgcn_mfma_f32_16x16x32_bf16(af1, bf1, acc[1][1], 0, 0, 0);
    __syncthreads();
  }

#pragma unroll
  for (int r = 0; r < 2; ++r) {
#pragma unroll
    for (int c = 0; c < 2; ++c) {
      int col = n0 + wc*32 + c*16 + l15;
      int rowb = m0 + wr*32 + r*16 + (lane >> 4)*4;
#pragma unroll
      for (int j = 0; j < 4; ++j) {
        int row = rowb + j;
        if (row < NPATCH)
          atomicAdd(C + (size_t)row*DM + col, acc[r][c][j]);
      }
    }
  }
}

// ---------------------------------------------------------------------------
// Fused LN + xz GEMM (K=192 fully in LDS, one barrier before 6 MFMA k-steps).
// blockIdx.x==0 blocks zero xdbl rows (atomic split-K cgemm downstream).
// ---------------------------------------------------------------------------
__global__ __launch_bounds__(256) void lnxz_kernel(
    const float* __restrict__ cur, const float* __restrict__ g,
    const float* __restrict__ b, const float* __restrict__ W,
    float* __restrict__ xz, float* __restrict__ xdbl_z) {
  __shared__ unsigned short As[64][200];
  __shared__ unsigned short Bs[64][200];
  __shared__ float gs[192], bs2[192];
  int tid = threadIdx.x;
  int m0 = blockIdx.y * 64, n0 = blockIdx.x * 64;
  int wave = tid >> 6, lane = tid & 63;
  int wr = wave >> 1, wc = wave & 1;
  int l15 = lane & 15, lk = (lane >> 4) * 8;

  for (int i = tid; i < 192; i += 256) { gs[i] = g[i]; bs2[i] = b[i]; }

  if (blockIdx.x == 0) {
    for (int i = tid; i < 64*11; i += 256) {
      int r = i / 11, q = i % 11;
      int row = m0 + r;
      if (row < L_TOK) {
        float4 z = {0.f,0.f,0.f,0.f};
        *(float4*)(xdbl_z + (size_t)row*XDBL_N + q*4) = z;
      }
    }
  }

  int r = tid >> 2, c0 = (tid & 3) * 48;
  float v[48];
  {
    int row = m0 + r;
    if (row < L_TOK) {
      const float* rp = cur + (size_t)row*DM + c0;
#pragma unroll
      for (int j = 0; j < 12; ++j) {
        float4 t4 = *(const float4*)(rp + j*4);
        v[j*4+0]=t4.x; v[j*4+1]=t4.y; v[j*4+2]=t4.z; v[j*4+3]=t4.w;
      }
    } else {
#pragma unroll
      for (int j = 0; j < 48; ++j) v[j] = 0.f;
    }
  }
  float s = 0.f, s2 = 0.f;
#pragma unroll
  for (int j = 0; j < 48; ++j) { s += v[j]; s2 += v[j]*v[j]; }
  s  += __shfl_xor(s, 1, 64); s2 += __shfl_xor(s2, 1, 64);
  s  += __shfl_xor(s, 2, 64); s2 += __shfl_xor(s2, 2, 64);
  float mu = s * (1.0f/192.0f);
  float var = s2 * (1.0f/192.0f) - mu*mu;
  float rsd = rsqrtf(var + 1e-5f);

  __syncthreads();
#pragma unroll
  for (int j = 0; j < 48; ++j) {
    int k = c0 + j;
    As[r][k] = f2bf((v[j] - mu)*rsd*gs[k] + bs2[k]);
  }
  {
    const float* rp = W + (size_t)(n0 + r)*DM + c0;
#pragma unroll
    for (int j = 0; j < 12; ++j) {
      float4 t4 = *(const float4*)(rp + j*4);
      Bs[r][c0+j*4+0]=f2bf(t4.x); Bs[r][c0+j*4+1]=f2bf(t4.y);
      Bs[r][c0+j*4+2]=f2bf(t4.z); Bs[r][c0+j*4+3]=f2bf(t4.w);
    }
  }
  __syncthreads();

  f32x4 acc[2][2];
#pragma unroll
  for (int i = 0; i < 2; ++i)
#pragma unroll
    for (int j = 0; j < 2; ++j) acc[i][j] = (f32x4){0.f,0.f,0.f,0.f};

#pragma unroll
  for (int kk = 0; kk < 6; ++kk) {
    short8 af0 = *(const short8*)&As[wr*32      + l15][kk*32 + lk];
    short8 af1 = *(const short8*)&As[wr*32 + 16 + l15][kk*32 + lk];
    short8 bf0 = *(const short8*)&Bs[wc*32      + l15][kk*32 + lk];
    short8 bf1 = *(const short8*)&Bs[wc*32 + 16 + l15][kk*32 + lk];
    acc[0][0] = __builtin_amdgcn_mfma_f32_16x16x32_bf16(af0, bf0, acc[0][0], 0, 0, 0);
    acc[0][1] = __builtin_amdgcn_mfma_f32_16x16x32_bf16(af0, bf1, acc[0][1], 0, 0, 0);
    acc[1][0] = __builtin_amdgcn_mfma_f32_16x16x32_bf16(af1, bf0, acc[1][0], 0, 0, 0);
    acc[1][1] = __builtin_amdgcn_mfma_f32_16x16x32_bf16(af1, bf1, acc[1][1], 0, 0, 0);
  }

#pragma unroll
  for (int rr = 0; rr < 2; ++rr) {
#pragma unroll
    for (int cc = 0; cc < 2; ++cc) {
      int col = n0 + wc*32 + cc*16 + l15;
      int rowb = m0 + wr*32 + rr*16 + (lane >> 4)*4;
#pragma unroll
      for (int j = 0; j < 4; ++j) {
        int row = rowb + j;
        if (row < L_TOK) xz[(size_t)row*(2*DI) + col] = acc[rr][cc][j];
      }
    }
  }
}

// ---------------------------------------------------------------------------
// xdbl GEMM, conv+SiLU fused in A-staging; split-K 12 (ksl=32, one k-step).
// Also exports u = silu(conv(xz)) to uc (f32) for the scan.
// grid = (1, 25, 12). xdbl zero-initialized by lnxz.
// ---------------------------------------------------------------------------
__global__ __launch_bounds__(256) void cgemm_kernel(
    const float* __restrict__ xz,
    const float* __restrict__ Wc, const float* __restrict__ bc,
    const float* __restrict__ B, float* __restrict__ C,
    float* __restrict__ uc) {
  __shared__ unsigned short As[64*40];
  __shared__ unsigned short Bs[64*40];
  __shared__ float wcs[32][4];
  __shared__ float bcs[32];
  const int M = L_TOK, N = XDBL_N;
  int tid = threadIdx.x;
  int m0 = blockIdx.y * 64;
  int kbase = blockIdx.z * 32;
  int wave = tid >> 6, lane = tid & 63;
  int wr = wave >> 1, wcq = wave & 1;
  int srow = tid >> 2;
  int skq  = (tid & 3) * 8;
  if (tid < 32) {
    *(float4*)wcs[tid] = *(const float4*)(Wc + (size_t)(kbase + tid)*4);
    bcs[tid] = bc[kbase + tid];
  }

  int t = m0 + srow;
  bool a_ok = (t < M);
  bool b_ok = (srow < N);
  const float* bp = B + (size_t)srow*DI + kbase + skq;
  const float4 z4 = {0.f,0.f,0.f,0.f};
  int l15 = lane & 15, lk = (lane >> 4) * 8;
  int cg = kbase + skq;

  float tap[4][8];
#pragma unroll
  for (int j = 0; j < 4; ++j) {
    int ts = t - 3 + j;
    float4 v0 = z4, v1 = z4;
    if (a_ok && ts >= 0) {
      v0 = *(const float4*)(xz + (size_t)ts*(2*DI) + cg);
      v1 = *(const float4*)(xz + (size_t)ts*(2*DI) + cg + 4);
    }
    tap[j][0]=v0.x; tap[j][1]=v0.y; tap[j][2]=v0.z; tap[j][3]=v0.w;
    tap[j][4]=v1.x; tap[j][5]=v1.y; tap[j][6]=v1.z; tap[j][7]=v1.w;
  }
  float4 bv0 = b_ok ? *(const float4*)(bp)     : z4;
  float4 bv1 = b_ok ? *(const float4*)(bp + 4) : z4;
  __syncthreads();   // wcs/bcs ready

  float uv[8];
  short8 pa, pb;
#pragma unroll
  for (int c = 0; c < 8; ++c) {
    float u = bcs[skq + c];
#pragma unroll
    for (int j = 0; j < 4; ++j) u = fmaf(tap[j][c], wcs[skq + c][j], u);
    u = u / (1.0f + expf(-u));
    uv[c] = u;
    pa[c] = (short)f2bf(u);
  }
  if (a_ok) {
    float4 o0 = {uv[0], uv[1], uv[2], uv[3]};
    float4 o1 = {uv[4], uv[5], uv[6], uv[7]};
    *(float4*)(uc + (size_t)t*DI + cg)     = o0;
    *(float4*)(uc + (size_t)t*DI + cg + 4) = o1;
  }
  pb[0]=f2bf(bv0.x); pb[1]=f2bf(bv0.y); pb[2]=f2bf(bv0.z); pb[3]=f2bf(bv0.w);
  pb[4]=f2bf(bv1.x); pb[5]=f2bf(bv1.y); pb[6]=f2bf(bv1.z); pb[7]=f2bf(bv1.w);
  *(short8*)&As[srow*40 + skq] = pa;
  *(short8*)&Bs[srow*40 + skq] = pb;
  __syncthreads();

  f32x4 acc[2][2];
#pragma unroll
  for (int i = 0; i < 2; ++i)
#pragma unroll
    for (int j = 0; j < 2; ++j) acc[i][j] = (f32x4){0.f,0.f,0.f,0.f};
  short8 af0 = *(const short8*)&As[(wr*32      + l15)*40 + lk];
  short8 af1 = *(const short8*)&As[(wr*32 + 16 + l15)*40 + lk];
  short8 bf0 = *(const short8*)&Bs[(wcq*32      + l15)*40 + lk];
  short8 bf1 = *(const short8*)&Bs[(wcq*32 + 16 + l15)*40 + lk];
  acc[0][0] = __builtin_amdgcn_mfma_f32_16x16x32_bf16(af0, bf0, acc[0][0], 0, 0, 0);
  acc[0][1] = __builtin_amdgcn_mfma_f32_16x16x32_bf16(af0, bf1, acc[0][1], 0, 0, 0);
  acc[1][0] = __builtin_amdgcn_mfma_f32_16x16x32_bf16(af1, bf0, acc[1][0], 0, 0, 0);
  acc[1][1] = __builtin_amdgcn_mfma_f32_16x16x32_bf16(af1, bf1, acc[1][1], 0, 0, 0);

#pragma unroll
  for (int r = 0; r < 2; ++r) {
#pragma unroll
    for (int c = 0; c < 2; ++c) {
      int col = wcq*32 + c*16 + l15;
      if (col >= N) continue;
      int rowb = m0 + wr*32 + r*16 + (lane >> 4)*4;
#pragma unroll
      for (int j = 0; j < 4; ++j) {
        int row = rowb + j;
        if (row >= M) continue;
        atomicAdd(C + (size_t)row*XDBL_N + col, acc[r][c][j]);
      }
    }
  }
}

// ---------------------------------------------------------------------------
// scan_p1: per-chunk local scan from zero state (CLEN=32). Exports delta.
// grid = (NDG, NCHUNK) = (24, 50), 256 thr = 16d x 16n.
// Padded loop: ds zeroed for t >= L_TOK -> dA = 1, state preserved.
// ---------------------------------------------------------------------------
__global__ __launch_bounds__(256) void scan_p1(
    const float* __restrict__ uc, const float* __restrict__ xdbl,
    const float* __restrict__ W_dt, const float* __restrict__ b_dt,
    const float* __restrict__ A_log,
    float* __restrict__ cP, float* __restrict__ cS,
    float* __restrict__ dlt) {
  __shared__ float us[CLEN][16], ds[CLEN][16], bs[CLEN][16];
  __shared__ float xd12[CLEN][12], wdt[16][12], bds[16];
  int tid = threadIdx.x;
  int dl = tid >> 4, n = tid & 15;
  int d0 = blockIdx.x * 16;
  int t0 = blockIdx.y * CLEN;

  for (int i = tid; i < CLEN*16; i += 256) {
    int tt = i >> 4, dd = i & 15;
    int t = t0 + tt;
    us[tt][dd] = (t < L_TOK) ? uc[(size_t)t*DI + d0 + dd] : 0.0f;
  }
  for (int i = tid; i < CLEN*28; i += 256) {
    int tt = i / 28, c = i % 28;
    int t = t0 + tt;
    float v = (t < L_TOK) ? xdbl[(size_t)t*XDBL_N + c] : 0.0f;
    if (c < 12) xd12[tt][c] = v;
    else bs[tt][c-12] = v;
  }
  if (tid < 192) wdt[tid/12][tid%12] = W_dt[(d0 + tid/12)*DTR + tid%12];
  if (tid < 16)  bds[tid] = b_dt[d0+tid];
  __syncthreads();
  for (int i = tid; i < CLEN*16; i += 256) {
    int tt = i >> 4, dd = i & 15;
    int t = t0 + tt;
    float v = 0.0f;
    if (t < L_TOK) {
      v = bds[dd];
#pragma unroll
      for (int r = 0; r < 12; ++r) v = fmaf(xd12[tt][r], wdt[dd][r], v);
      v = (v > 20.0f) ? v : log1pf(expf(v));
      dlt[(size_t)t*DI + d0 + dd] = v;
    }
    ds[tt][dd] = v;
  }
  __syncthreads();

  int d = d0 + dl;
  float a2 = -expf(A_log[d*DS + n]) * 1.44269504088896340736f;
  float s = 0.0f, P = 1.0f;
#pragma unroll 4
  for (int tt = 0; tt < CLEN; ++tt) {
    float dv = ds[tt][dl];
    float dA = exp2f(dv * a2);
    s = fmaf(dA, s, dv * bs[tt][n] * us[tt][dl]);
    P *= dA;
  }
  int o = (blockIdx.y * DI + d) * DS + n;
  cP[o] = P;
  cS[o] = s;
}

// ---------------------------------------------------------------------------
// scan_p3: carry-in combine over preceding chunks, re-scan, emit y (gated).
// grid = (NDG, NCHUNK) = (24, 50), 256 thr.
// ---------------------------------------------------------------------------
__global__ __launch_bounds__(256) void scan_p3(
    const float* __restrict__ uc, const float* __restrict__ dlt,
    const float* __restrict__ xdbl, const float* __restrict__ xz,
    const float* __restrict__ A_log, const float* __restrict__ Dp,
    const float* __restrict__ cP, const float* __restrict__ cS,
    float* __restrict__ yy) {
  __shared__ float us[CLEN][16], ds[CLEN][16], bs[CLEN][16];
  __shared__ float cs[CLEN][16], zs[CLEN][16];
  int tid = threadIdx.x;
  int dl = tid >> 4, n = tid & 15;
  int d0 = blockIdx.x * 16;
  int cidx = blockIdx.y;
  int t0 = cidx * CLEN;
  int nt = min(CLEN, L_TOK - t0);
  int d = d0 + dl;

  float s = 0.0f;
  {
    int oo = d * DS + n;
    for (int c2 = 0; c2 < cidx; ++c2)
      s = fmaf(cP[(size_t)c2*(DI*DS) + oo], s, cS[(size_t)c2*(DI*DS) + oo]);
  }

  for (int i = tid; i < CLEN*16; i += 256) {
    int tt = i >> 4, dd = i & 15;
    int t = t0 + tt;
    bool ok = (t < L_TOK);
    us[tt][dd] = ok ? uc[(size_t)t*DI + d0 + dd] : 0.f;
    ds[tt][dd] = ok ? dlt[(size_t)t*DI + d0 + dd] : 0.f;
    zs[tt][dd] = ok ? xz[(size_t)t*(2*DI) + DI + d0 + dd] : 0.f;
  }
  for (int i = tid; i < CLEN*32; i += 256) {
    int tt = i >> 5, cq = i & 31;
    int t = t0 + tt;
    float v = (t < L_TOK) ? xdbl[(size_t)t*XDBL_N + 12 + cq] : 0.f;
    if (cq < 16) bs[tt][cq] = v;
    else cs[tt][cq-16] = v;
  }
  __syncthreads();

  float a2 = -expf(A_log[d*DS + n]) * 1.44269504088896340736f;
  float dpv = Dp[d];
#pragma unroll 4
  for (int tt = 0; tt < CLEN; ++tt) {
    float dv = ds[tt][dl], uu = us[tt][dl];
    float dA = exp2f(dv * a2);
    s = fmaf(dA, s, dv * bs[tt][n] * uu);
    float p = s * cs[tt][n];
    p += __shfl_xor(p, 1, 64);
    p += __shfl_xor(p, 2, 64);
    p += __shfl_xor(p, 4, 64);
    p += __shfl_xor(p, 8, 64);
    if (n == 0 && tt < nt) {
      float z = zs[tt][dl];
      float y = fmaf(uu, dpv, p);
      y *= z / (1.0f + expf(-z));
      yy[(size_t)(t0 + tt)*DI + d] = y;
    }
  }
}

// ---------------------------------------------------------------------------
// out projection: cur += yy @ W_out^T, M=1569, N=192, K=384, split-K 4,
// atomicAdd residual into cur.
// ---------------------------------------------------------------------------
__global__ __launch_bounds__(256) void mgemm_kernel(
    const float* __restrict__ A, int lda,
    const float* __restrict__ B, int ldb,
    float* __restrict__ C, int ldc,
    int M, int N, int ksl) {
  __shared__ unsigned short As[64*40];
  __shared__ unsigned short Bs[64*40];
  int tid = threadIdx.x;
  int m0 = blockIdx.y * 64, n0 = blockIdx.x * 64;
  int kbase = blockIdx.z * ksl;
  int wave = tid >> 6, lane = tid & 63;
  int wr = wave >> 1, wc = wave & 1;
  int srow = tid >> 2;
  int skq  = (tid & 3) * 8;
  f32x4 acc[2][2];
#pragma unroll
  for (int i = 0; i < 2; ++i)
#pragma unroll
    for (int j = 0; j < 2; ++j) acc[i][j] = (f32x4){0.f,0.f,0.f,0.f};

  int am = m0 + srow;
  int bn = n0 + srow;
  bool a_ok = (am < M), b_ok = (bn < N);
  const float* ap = A + (size_t)am*lda + kbase + skq;
  const float* bp = B + (size_t)bn*ldb + kbase + skq;
  const float4 z4 = {0.f,0.f,0.f,0.f};
  int l15 = lane & 15, lk = (lane >> 4) * 8;

  int nt = ksl >> 5;
  float4 a0 = a_ok ? *(const float4*)(ap)     : z4;
  float4 a1 = a_ok ? *(const float4*)(ap + 4) : z4;
  float4 b0 = b_ok ? *(const float4*)(bp)     : z4;
  float4 b1 = b_ok ? *(const float4*)(bp + 4) : z4;

  for (int i = 0; i < nt; ++i) {
    {
      short8 pa, pb;
      pa[0]=f2bf(a0.x); pa[1]=f2bf(a0.y); pa[2]=f2bf(a0.z); pa[3]=f2bf(a0.w);
      pa[4]=f2bf(a1.x); pa[5]=f2bf(a1.y); pa[6]=f2bf(a1.z); pa[7]=f2bf(a1.w);
      pb[0]=f2bf(b0.x); pb[1]=f2bf(b0.y); pb[2]=f2bf(b0.z); pb[3]=f2bf(b0.w);
      pb[4]=f2bf(b1.x); pb[5]=f2bf(b1.y); pb[6]=f2bf(b1.z); pb[7]=f2bf(b1.w);
      *(short8*)&As[srow*40 + skq] = pa;
      *(short8*)&Bs[srow*40 + skq] = pb;
    }
    __syncthreads();
    bool pf = (i + 1 < nt);
    int k0n = (i + 1) << 5;
    a0 = (pf && a_ok) ? *(const float4*)(ap + k0n)     : z4;
    a1 = (pf && a_ok) ? *(const float4*)(ap + k0n + 4) : z4;
    b0 = (pf && b_ok) ? *(const float4*)(bp + k0n)     : z4;
    b1 = (pf && b_ok) ? *(const float4*)(bp + k0n + 4) : z4;

    short8 af0 = *(const short8*)&As[(wr*32      + l15)*40 + lk];
    short8 af1 = *(const short8*)&As[(wr*32 + 16 + l15)*40 + lk];
    short8 bf0 = *(const short8*)&Bs[(wc*32      + l15)*40 + lk];
    short8 bf1 = *(const short8*)&Bs[(wc*32 + 16 + l15)*40 + lk];
    acc[0][0] = __builtin_amdgcn_mfma_f32_16x16x32_bf16(af0, bf0, acc[0][0], 0, 0, 0);
    acc[0][1] = __builtin_amdgcn_mfma_f32_16x16x32_bf16(af0, bf1, acc[0][1], 0, 0, 0);
    acc[1][0] = __builtin_amdgcn_mfma_f32_16x16x32_bf16(af1, bf0, acc[1][0], 0, 0, 0);
    acc[1][1] = __builtin_amdgcn_mfma_f32_16x16x32_bf16(af1, bf1, acc[1][1], 0, 0, 0);
    __syncthreads();
  }

#pragma unroll
  for (int r = 0; r < 2; ++r) {
#pragma unroll
    for (int c = 0; c < 2; ++c) {
      int col = n0 + wc*32 + c*16 + l15;
      if (col >= N) continue;
      int rowb = m0 + wr*32 + r*16 + (lane >> 4)*4;
#pragma unroll
      for (int j = 0; j < 4; ++j) {
        int row = rowb + j;
        if (row >= M) continue;
        atomicAdd(C + (size_t)row*ldc + col, acc[r][c][j]);
      }
    }
  }
}

// ---------------------------------------------------------------------------
extern "C" void kernel_launch(void* const* d_in, const int* in_sizes, int n_in,
                              void* d_out, int out_size, void* d_ws, size_t ws_size,
                              hipStream_t stream) {
  const float* x       = (const float*)d_in[0];
  const float* patch_w = (const float*)d_in[1];
  const float* patch_b = (const float*)d_in[2];
  const float* cls_tok = (const float*)d_in[3];
  const float* pos_emb = (const float*)d_in[4];
  const float* ln_g    = (const float*)d_in[5];
  const float* ln_b    = (const float*)d_in[6];
  const float* W_in    = (const float*)d_in[7];
  const float* Wc      = (const float*)d_in[8];
  const float* bc      = (const float*)d_in[9];
  const float* Wx      = (const float*)d_in[10];
  const float* W_dt    = (const float*)d_in[11];
  const float* b_dt    = (const float*)d_in[12];
  const float* A_log   = (const float*)d_in[13];
  const float* Dp      = (const float*)d_in[14];
  const float* W_out   = (const float*)d_in[15];
  const float* fn_g    = (const float*)d_in[16];
  const float* fn_b    = (const float*)d_in[17];

  float* ws = (float*)d_ws;
  float* cur   = ws;                       // 1569*192
  float* xz    = cur   + L_TOK*DM;         // 1569*768
  float* xdbl  = xz    + L_TOK*2*DI;       // 1569*44
  float* uc    = xdbl  + L_TOK*XDBL_N;     // 1569*384
  float* dlt   = uc    + L_TOK*DI;         // 1569*384
  float* yy    = dlt   + L_TOK*DI;         // 1569*384
  float* cP    = yy    + L_TOK*DI;         // 50*6144
  float* cS    = cP    + NCHUNK*DI*DS;

  init_kernel<<<(L_TOK*DM/4 + 255)/256, 256, 0, stream>>>(
      cls_tok, patch_b, pos_emb, cur);
  {
    dim3 grid(DM/64, (NPATCH + 63)/64, 4);
    patch_gemm<<<grid, 256, 0, stream>>>(x, patch_w, cur + DM);
  }

  for (int dep = 0; dep < DEPTH; ++dep) {
    const float* g     = ln_g  + dep*DM;
    const float* bb    = ln_b  + dep*DM;
    const float* Win_l = W_in  + (size_t)dep*2*DI*DM;
    const float* Wc_l  = Wc    + (size_t)dep*DI*DCONV;
    const float* bc_l  = bc    + (size_t)dep*DI;
    const float* Wx_l  = Wx    + (size_t)dep*XDBL_N*DI;
    const float* Wdt_l = W_dt  + (size_t)dep*DI*DTR;
    const float* bdt_l = b_dt  + (size_t)dep*DI;
    const float* Alog_l= A_log + (size_t)dep*DI*DS;
    const float* Dp_l  = Dp    + (size_t)dep*DI;
    const float* Wout_l= W_out + (size_t)dep*DM*DI;

    // xz = LN(cur) @ W_in^T (fused; zeroes xdbl)
    {
      dim3 grid((2*DI)/64, (L_TOK + 63)/64);
      lnxz_kernel<<<grid, 256, 0, stream>>>(cur, g, bb, Win_l, xz, xdbl);
    }
    // xdbl = silu(conv(u)) @ Wx^T, split-K 12; exports uc
    {
      dim3 grid(1, (L_TOK + 63)/64, 12);
      cgemm_kernel<<<grid, 256, 0, stream>>>(xz, Wc_l, bc_l, Wx_l, xdbl, uc);
    }
    // selective scan: local (p1, exports delta) then carry+emit (p3)
    {
      dim3 g1(NDG, NCHUNK);
      scan_p1<<<g1, 256, 0, stream>>>(uc, xdbl, Wdt_l, bdt_l, Alog_l, cP, cS, dlt);
      scan_p3<<<g1, 256, 0, stream>>>(uc, dlt, xdbl, xz, Alog_l, Dp_l, cP, cS, yy);
    }
    // cur += yy @ W_out^T
    {
      dim3 grid(DM/64, (L_TOK + 63)/64, 4);
      mgemm_kernel<<<grid, 256, 0, stream>>>(yy, DI, Wout_l, DI, cur, DM,
                                             L_TOK, DM, DI/4);
    }
  }

  ln_kernel<<<L_TOK, 64, 0, stream>>>(cur, (float*)d_out, fn_g, fn_b);
}

// Round 13
// 542.775 us; speedup vs baseline: 4.6342x; 1.0812x over previous
//
#include <hip/hip_runtime.h>
#include <hip/hip_bf16.h>
#include <math.h>

#define L_TOK 1569
#define DM 192
#define DI 384
#define DS 16
#define DTR 12
#define DCONV 4
#define XDBL_N (DTR + 2*DS)   // 44
#define DEPTH 8
#define NCHUNK 50
#define CLEN 32
#define NPATCH 1568
#define NDG 24                // scan d-groups (384/16)

typedef __attribute__((ext_vector_type(8))) short short8;
typedef __attribute__((ext_vector_type(8))) unsigned short us8;
typedef __attribute__((ext_vector_type(4))) float f32x4;

__device__ __forceinline__ unsigned short f2bf(float f) {
  unsigned int u = __float_as_uint(f);
  u += 0x7FFFu + ((u >> 16) & 1u);   // round-to-nearest-even
  return (unsigned short)(u >> 16);
}

__device__ __forceinline__ float bf2f(unsigned short h) {
  return __uint_as_float(((unsigned int)h) << 16);
}

// ---------------------------------------------------------------------------
// cur init: cur[tok][e] = pos[tok][e] + (tok==0 ? cls[e] : patch_b[e]).
// ---------------------------------------------------------------------------
__global__ __launch_bounds__(256) void init_kernel(
    const float* __restrict__ cls, const float* __restrict__ pb,
    const float* __restrict__ pos, float* __restrict__ curp) {
  int gid = blockIdx.x * 256 + threadIdx.x;
  const int initN = (L_TOK * DM) / 4;
  if (gid >= initN) return;
  int e4 = gid * 4;
  int tok = e4 / DM;
  int col = e4 % DM;
  float4 pv = *(const float4*)(pos + e4);
  float4 av = (tok == 0) ? *(const float4*)(cls + col)
                         : *(const float4*)(pb + col);
  float4 o = {pv.x + av.x, pv.y + av.y, pv.z + av.z, pv.w + av.w};
  *(float4*)(curp + e4) = o;
}

// ---------------------------------------------------------------------------
// Final LayerNorm. One wave per token.
// ---------------------------------------------------------------------------
__global__ __launch_bounds__(64) void ln_kernel(
    const float* __restrict__ in, float* __restrict__ out,
    const float* __restrict__ g, const float* __restrict__ b) {
  int tokn = blockIdx.x;
  int lane = threadIdx.x;
  const float* row = in + (size_t)tokn*DM;
  float x0 = row[lane], x1 = row[lane+64], x2 = row[lane+128];
  float s = x0 + x1 + x2;
  float s2 = x0*x0 + x1*x1 + x2*x2;
#pragma unroll
  for (int off = 1; off < 64; off <<= 1) {
    s  += __shfl_xor(s,  off, 64);
    s2 += __shfl_xor(s2, off, 64);
  }
  float m = s * (1.0f/192.0f);
  float v = s2 * (1.0f/192.0f) - m*m;
  float rs = rsqrtf(v + 1e-5f);
  float* orow = out + (size_t)tokn*DM;
  orow[lane]     = (x0 - m)*rs*g[lane]     + b[lane];
  orow[lane+64]  = (x1 - m)*rs*g[lane+64]  + b[lane+64];
  orow[lane+128] = (x2 - m)*rs*g[lane+128] + b[lane+128];
}

// ---------------------------------------------------------------------------
// Patch GEMM, im2col fused into A-staging: cur[1..][:] += X_patch @ patch_w^T.
// M=1568, N=192, K=768, split-K 4 (ksl=192), atomicAdd (cur pre-init).
// ---------------------------------------------------------------------------
__device__ __forceinline__ float4 ldx4(const float* __restrict__ x,
                                       int pt, int hh, int w, int k) {
  int c = k >> 8, p = (k >> 4) & 15, q = k & 15;
  return *(const float4*)(x + ((size_t)(c*8 + pt)*224 + hh*16 + p)*224
                            + w*16 + q);
}

__global__ __launch_bounds__(256) void patch_gemm(
    const float* __restrict__ x, const float* __restrict__ pw,
    float* __restrict__ C) {
  __shared__ unsigned short As[64*40];
  __shared__ unsigned short Bs[64*40];
  int tid = threadIdx.x;
  int m0 = blockIdx.y * 64, n0 = blockIdx.x * 64;
  int kbase = blockIdx.z * 192;
  int wave = tid >> 6, lane = tid & 63;
  int wr = wave >> 1, wc = wave & 1;
  int srow = tid >> 2;
  int skq  = (tid & 3) * 8;
  f32x4 acc[2][2];
#pragma unroll
  for (int i = 0; i < 2; ++i)
#pragma unroll
    for (int j = 0; j < 2; ++j) acc[i][j] = (f32x4){0.f,0.f,0.f,0.f};

  int am = m0 + srow;
  bool a_ok = (am < NPATCH);
  int am_s = a_ok ? am : 0;
  int pt = am_s / 196, hw = am_s % 196, hh = hw / 14, w = hw % 14;
  int bn = n0 + srow;
  const float* bp = pw + (size_t)bn*768 + kbase + skq;
  const float4 z4 = {0.f,0.f,0.f,0.f};
  int l15 = lane & 15, lk = (lane >> 4) * 8;

  const int nt = 6;   // 192/32
  float4 a0 = a_ok ? ldx4(x, pt, hh, w, kbase + skq)     : z4;
  float4 a1 = a_ok ? ldx4(x, pt, hh, w, kbase + skq + 4) : z4;
  float4 b0 = *(const float4*)(bp);
  float4 b1 = *(const float4*)(bp + 4);

  for (int i = 0; i < nt; ++i) {
    {
      short8 pa, pb;
      pa[0]=f2bf(a0.x); pa[1]=f2bf(a0.y); pa[2]=f2bf(a0.z); pa[3]=f2bf(a0.w);
      pa[4]=f2bf(a1.x); pa[5]=f2bf(a1.y); pa[6]=f2bf(a1.z); pa[7]=f2bf(a1.w);
      pb[0]=f2bf(b0.x); pb[1]=f2bf(b0.y); pb[2]=f2bf(b0.z); pb[3]=f2bf(b0.w);
      pb[4]=f2bf(b1.x); pb[5]=f2bf(b1.y); pb[6]=f2bf(b1.z); pb[7]=f2bf(b1.w);
      *(short8*)&As[srow*40 + skq] = pa;
      *(short8*)&Bs[srow*40 + skq] = pb;
    }
    __syncthreads();
    bool pf = (i + 1 < nt);
    int kn = kbase + ((i + 1) << 5) + skq;
    a0 = (pf && a_ok) ? ldx4(x, pt, hh, w, kn)     : z4;
    a1 = (pf && a_ok) ? ldx4(x, pt, hh, w, kn + 4) : z4;
    b0 = pf ? *(const float4*)(bp + ((i+1)<<5))     : z4;
    b1 = pf ? *(const float4*)(bp + ((i+1)<<5) + 4) : z4;

    short8 af0 = *(const short8*)&As[(wr*32      + l15)*40 + lk];
    short8 af1 = *(const short8*)&As[(wr*32 + 16 + l15)*40 + lk];
    short8 bf0 = *(const short8*)&Bs[(wc*32      + l15)*40 + lk];
    short8 bf1 = *(const short8*)&Bs[(wc*32 + 16 + l15)*40 + lk];
    acc[0][0] = __builtin_amdgcn_mfma_f32_16x16x32_bf16(af0, bf0, acc[0][0], 0, 0, 0);
    acc[0][1] = __builtin_amdgcn_mfma_f32_16x16x32_bf16(af0, bf1, acc[0][1], 0, 0, 0);
    acc[1][0] = __builtin_amdgcn_mfma_f32_16x16x32_bf16(af1, bf0, acc[1][0], 0, 0, 0);
    acc[1][1] = __builtin_amdgcn_mfma_f32_16x16x32_bf16(af1, bf1, acc[1][1], 0, 0, 0);
    __syncthreads();
  }

#pragma unroll
  for (int r = 0; r < 2; ++r) {
#pragma unroll
    for (int c = 0; c < 2; ++c) {
      int col = n0 + wc*32 + c*16 + l15;
      int rowb = m0 + wr*32 + r*16 + (lane >> 4)*4;
#pragma unroll
      for (int j = 0; j < 4; ++j) {
        int row = rowb + j;
        if (row < NPATCH)
          atomicAdd(C + (size_t)row*DM + col, acc[r][c][j]);
      }
    }
  }
}

// ---------------------------------------------------------------------------
// Fused LN + xz GEMM; output xz stored as bf16. Zeroes xdbl (bx==0).
// ---------------------------------------------------------------------------
__global__ __launch_bounds__(256) void lnxz_kernel(
    const float* __restrict__ cur, const float* __restrict__ g,
    const float* __restrict__ b, const float* __restrict__ W,
    unsigned short* __restrict__ xzb, float* __restrict__ xdbl_z) {
  __shared__ unsigned short As[64][200];
  __shared__ unsigned short Bs[64][200];
  __shared__ float gs[192], bs2[192];
  int tid = threadIdx.x;
  int m0 = blockIdx.y * 64, n0 = blockIdx.x * 64;
  int wave = tid >> 6, lane = tid & 63;
  int wr = wave >> 1, wc = wave & 1;
  int l15 = lane & 15, lk = (lane >> 4) * 8;

  for (int i = tid; i < 192; i += 256) { gs[i] = g[i]; bs2[i] = b[i]; }

  if (blockIdx.x == 0) {
    for (int i = tid; i < 64*11; i += 256) {
      int r = i / 11, q = i % 11;
      int row = m0 + r;
      if (row < L_TOK) {
        float4 z = {0.f,0.f,0.f,0.f};
        *(float4*)(xdbl_z + (size_t)row*XDBL_N + q*4) = z;
      }
    }
  }

  int r = tid >> 2, c0 = (tid & 3) * 48;
  float v[48];
  {
    int row = m0 + r;
    if (row < L_TOK) {
      const float* rp = cur + (size_t)row*DM + c0;
#pragma unroll
      for (int j = 0; j < 12; ++j) {
        float4 t4 = *(const float4*)(rp + j*4);
        v[j*4+0]=t4.x; v[j*4+1]=t4.y; v[j*4+2]=t4.z; v[j*4+3]=t4.w;
      }
    } else {
#pragma unroll
      for (int j = 0; j < 48; ++j) v[j] = 0.f;
    }
  }
  float s = 0.f, s2 = 0.f;
#pragma unroll
  for (int j = 0; j < 48; ++j) { s += v[j]; s2 += v[j]*v[j]; }
  s  += __shfl_xor(s, 1, 64); s2 += __shfl_xor(s2, 1, 64);
  s  += __shfl_xor(s, 2, 64); s2 += __shfl_xor(s2, 2, 64);
  float mu = s * (1.0f/192.0f);
  float var = s2 * (1.0f/192.0f) - mu*mu;
  float rsd = rsqrtf(var + 1e-5f);

  __syncthreads();
#pragma unroll
  for (int j = 0; j < 48; ++j) {
    int k = c0 + j;
    As[r][k] = f2bf((v[j] - mu)*rsd*gs[k] + bs2[k]);
  }
  {
    const float* rp = W + (size_t)(n0 + r)*DM + c0;
#pragma unroll
    for (int j = 0; j < 12; ++j) {
      float4 t4 = *(const float4*)(rp + j*4);
      Bs[r][c0+j*4+0]=f2bf(t4.x); Bs[r][c0+j*4+1]=f2bf(t4.y);
      Bs[r][c0+j*4+2]=f2bf(t4.z); Bs[r][c0+j*4+3]=f2bf(t4.w);
    }
  }
  __syncthreads();

  f32x4 acc[2][2];
#pragma unroll
  for (int i = 0; i < 2; ++i)
#pragma unroll
    for (int j = 0; j < 2; ++j) acc[i][j] = (f32x4){0.f,0.f,0.f,0.f};

#pragma unroll
  for (int kk = 0; kk < 6; ++kk) {
    short8 af0 = *(const short8*)&As[wr*32      + l15][kk*32 + lk];
    short8 af1 = *(const short8*)&As[wr*32 + 16 + l15][kk*32 + lk];
    short8 bf0 = *(const short8*)&Bs[wc*32      + l15][kk*32 + lk];
    short8 bf1 = *(const short8*)&Bs[wc*32 + 16 + l15][kk*32 + lk];
    acc[0][0] = __builtin_amdgcn_mfma_f32_16x16x32_bf16(af0, bf0, acc[0][0], 0, 0, 0);
    acc[0][1] = __builtin_amdgcn_mfma_f32_16x16x32_bf16(af0, bf1, acc[0][1], 0, 0, 0);
    acc[1][0] = __builtin_amdgcn_mfma_f32_16x16x32_bf16(af1, bf0, acc[1][0], 0, 0, 0);
    acc[1][1] = __builtin_amdgcn_mfma_f32_16x16x32_bf16(af1, bf1, acc[1][1], 0, 0, 0);
  }

#pragma unroll
  for (int rr = 0; rr < 2; ++rr) {
#pragma unroll
    for (int cc = 0; cc < 2; ++cc) {
      int col = n0 + wc*32 + cc*16 + l15;
      int rowb = m0 + wr*32 + rr*16 + (lane >> 4)*4;
#pragma unroll
      for (int j = 0; j < 4; ++j) {
        int row = rowb + j;
        if (row < L_TOK)
          xzb[(size_t)row*(2*DI) + col] = f2bf(acc[rr][cc][j]);
      }
    }
  }
}

// ---------------------------------------------------------------------------
// xdbl GEMM, conv+SiLU fused in A-staging; split-K 12 (ksl=32, one k-step).
// xz is bf16; exports u (bf16) to ucb. xdbl (f32) zero-init by lnxz.
// grid = (1, 25, 12).
// ---------------------------------------------------------------------------
__global__ __launch_bounds__(256) void cgemm_kernel(
    const unsigned short* __restrict__ xzb,
    const float* __restrict__ Wc, const float* __restrict__ bc,
    const float* __restrict__ B, float* __restrict__ C,
    unsigned short* __restrict__ ucb) {
  __shared__ unsigned short As[64*40];
  __shared__ unsigned short Bs[64*40];
  __shared__ float wcs[32][4];
  __shared__ float bcs[32];
  const int M = L_TOK, N = XDBL_N;
  int tid = threadIdx.x;
  int m0 = blockIdx.y * 64;
  int kbase = blockIdx.z * 32;
  int wave = tid >> 6, lane = tid & 63;
  int wr = wave >> 1, wcq = wave & 1;
  int srow = tid >> 2;
  int skq  = (tid & 3) * 8;
  if (tid < 32) {
    *(float4*)wcs[tid] = *(const float4*)(Wc + (size_t)(kbase + tid)*4);
    bcs[tid] = bc[kbase + tid];
  }

  int t = m0 + srow;
  bool a_ok = (t < M);
  bool b_ok = (srow < N);
  const float* bp = B + (size_t)srow*DI + kbase + skq;
  const float4 z4 = {0.f,0.f,0.f,0.f};
  const us8 z8 = {0,0,0,0,0,0,0,0};
  int l15 = lane & 15, lk = (lane >> 4) * 8;
  int cg = kbase + skq;

  us8 tap[4];
#pragma unroll
  for (int j = 0; j < 4; ++j) {
    int ts = t - 3 + j;
    tap[j] = (a_ok && ts >= 0)
               ? *(const us8*)(xzb + (size_t)ts*(2*DI) + cg) : z8;
  }
  float4 bv0 = b_ok ? *(const float4*)(bp)     : z4;
  float4 bv1 = b_ok ? *(const float4*)(bp + 4) : z4;
  __syncthreads();   // wcs/bcs ready

  short8 pa, pb;
#pragma unroll
  for (int c = 0; c < 8; ++c) {
    float u = bcs[skq + c];
#pragma unroll
    for (int j = 0; j < 4; ++j)
      u = fmaf(bf2f(tap[j][c]), wcs[skq + c][j], u);
    u = u / (1.0f + expf(-u));
    pa[c] = (short)f2bf(u);
  }
  if (a_ok)
    *(short8*)(ucb + (size_t)t*DI + cg) = pa;
  pb[0]=f2bf(bv0.x); pb[1]=f2bf(bv0.y); pb[2]=f2bf(bv0.z); pb[3]=f2bf(bv0.w);
  pb[4]=f2bf(bv1.x); pb[5]=f2bf(bv1.y); pb[6]=f2bf(bv1.z); pb[7]=f2bf(bv1.w);
  *(short8*)&As[srow*40 + skq] = pa;
  *(short8*)&Bs[srow*40 + skq] = pb;
  __syncthreads();

  f32x4 acc[2][2];
#pragma unroll
  for (int i = 0; i < 2; ++i)
#pragma unroll
    for (int j = 0; j < 2; ++j) acc[i][j] = (f32x4){0.f,0.f,0.f,0.f};
  short8 af0 = *(const short8*)&As[(wr*32      + l15)*40 + lk];
  short8 af1 = *(const short8*)&As[(wr*32 + 16 + l15)*40 + lk];
  short8 bf0 = *(const short8*)&Bs[(wcq*32      + l15)*40 + lk];
  short8 bf1 = *(const short8*)&Bs[(wcq*32 + 16 + l15)*40 + lk];
  acc[0][0] = __builtin_amdgcn_mfma_f32_16x16x32_bf16(af0, bf0, acc[0][0], 0, 0, 0);
  acc[0][1] = __builtin_amdgcn_mfma_f32_16x16x32_bf16(af0, bf1, acc[0][1], 0, 0, 0);
  acc[1][0] = __builtin_amdgcn_mfma_f32_16x16x32_bf16(af1, bf0, acc[1][0], 0, 0, 0);
  acc[1][1] = __builtin_amdgcn_mfma_f32_16x16x32_bf16(af1, bf1, acc[1][1], 0, 0, 0);

#pragma unroll
  for (int r = 0; r < 2; ++r) {
#pragma unroll
    for (int c = 0; c < 2; ++c) {
      int col = wcq*32 + c*16 + l15;
      if (col >= N) continue;
      int rowb = m0 + wr*32 + r*16 + (lane >> 4)*4;
#pragma unroll
      for (int j = 0; j < 4; ++j) {
        int row = rowb + j;
        if (row >= M) continue;
        atomicAdd(C + (size_t)row*XDBL_N + col, acc[r][c][j]);
      }
    }
  }
}

// ---------------------------------------------------------------------------
// scan_p1: per-chunk local scan from zero state (CLEN=32). Exports delta bf16.
// grid = (NDG, NCHUNK) = (24, 50), 256 thr = 16d x 16n.
// ---------------------------------------------------------------------------
__global__ __launch_bounds__(256) void scan_p1(
    const unsigned short* __restrict__ ucb, const float* __restrict__ xdbl,
    const float* __restrict__ W_dt, const float* __restrict__ b_dt,
    const float* __restrict__ A_log,
    float* __restrict__ cP, float* __restrict__ cS,
    unsigned short* __restrict__ dltb) {
  __shared__ float us[CLEN][16], ds[CLEN][16], bs[CLEN][16];
  __shared__ float xd12[CLEN][12], wdt[16][12], bds[16];
  int tid = threadIdx.x;
  int dl = tid >> 4, n = tid & 15;
  int d0 = blockIdx.x * 16;
  int t0 = blockIdx.y * CLEN;
  const us8 z8 = {0,0,0,0,0,0,0,0};

  for (int i = tid; i < CLEN*2; i += 256) {
    int tt = i >> 1, h = (i & 1) * 8;
    int t = t0 + tt;
    us8 v = (t < L_TOK) ? *(const us8*)(ucb + (size_t)t*DI + d0 + h) : z8;
#pragma unroll
    for (int j = 0; j < 8; ++j) us[tt][h+j] = bf2f(v[j]);
  }
  for (int i = tid; i < CLEN*28; i += 256) {
    int tt = i / 28, c = i % 28;
    int t = t0 + tt;
    float v = (t < L_TOK) ? xdbl[(size_t)t*XDBL_N + c] : 0.0f;
    if (c < 12) xd12[tt][c] = v;
    else bs[tt][c-12] = v;
  }
  if (tid < 192) wdt[tid/12][tid%12] = W_dt[(d0 + tid/12)*DTR + tid%12];
  if (tid < 16)  bds[tid] = b_dt[d0+tid];
  __syncthreads();
  for (int i = tid; i < CLEN*16; i += 256) {
    int tt = i >> 4, dd = i & 15;
    int t = t0 + tt;
    float v = 0.0f;
    if (t < L_TOK) {
      v = bds[dd];
#pragma unroll
      for (int r = 0; r < 12; ++r) v = fmaf(xd12[tt][r], wdt[dd][r], v);
      v = (v > 20.0f) ? v : log1pf(expf(v));
      unsigned short hb = f2bf(v);
      dltb[(size_t)t*DI + d0 + dd] = hb;
      v = bf2f(hb);   // use rounded value so p1/p3 scans agree exactly
    }
    ds[tt][dd] = v;
  }
  __syncthreads();

  int d = d0 + dl;
  float a2 = -expf(A_log[d*DS + n]) * 1.44269504088896340736f;
  float s = 0.0f, P = 1.0f;
#pragma unroll 4
  for (int tt = 0; tt < CLEN; ++tt) {
    float dv = ds[tt][dl];
    float dA = exp2f(dv * a2);
    s = fmaf(dA, s, dv * bs[tt][n] * us[tt][dl]);
    P *= dA;
  }
  int o = (blockIdx.y * DI + d) * DS + n;
  cP[o] = P;
  cS[o] = s;
}

// ---------------------------------------------------------------------------
// scan_p3: carry-in combine over preceding chunks, re-scan, emit y (bf16).
// grid = (NDG, NCHUNK) = (24, 50), 256 thr.
// ---------------------------------------------------------------------------
__global__ __launch_bounds__(256) void scan_p3(
    const unsigned short* __restrict__ ucb,
    const unsigned short* __restrict__ dltb,
    const float* __restrict__ xdbl, const unsigned short* __restrict__ xzb,
    const float* __restrict__ A_log, const float* __restrict__ Dp,
    const float* __restrict__ cP, const float* __restrict__ cS,
    unsigned short* __restrict__ yyb) {
  __shared__ float us[CLEN][16], ds[CLEN][16], bs[CLEN][16];
  __shared__ float cs[CLEN][16], zs[CLEN][16];
  int tid = threadIdx.x;
  int dl = tid >> 4, n = tid & 15;
  int d0 = blockIdx.x * 16;
  int cidx = blockIdx.y;
  int t0 = cidx * CLEN;
  int nt = min(CLEN, L_TOK - t0);
  int d = d0 + dl;
  const us8 z8 = {0,0,0,0,0,0,0,0};

  float s = 0.0f;
  {
    int oo = d * DS + n;
    for (int c2 = 0; c2 < cidx; ++c2)
      s = fmaf(cP[(size_t)c2*(DI*DS) + oo], s, cS[(size_t)c2*(DI*DS) + oo]);
  }

  for (int i = tid; i < CLEN*2; i += 256) {
    int tt = i >> 1, h = (i & 1) * 8;
    int t = t0 + tt;
    bool ok = (t < L_TOK);
    us8 vu = ok ? *(const us8*)(ucb  + (size_t)t*DI + d0 + h) : z8;
    us8 vd = ok ? *(const us8*)(dltb + (size_t)t*DI + d0 + h) : z8;
    us8 vz = ok ? *(const us8*)(xzb  + (size_t)t*(2*DI) + DI + d0 + h) : z8;
#pragma unroll
    for (int j = 0; j < 8; ++j) {
      us[tt][h+j] = bf2f(vu[j]);
      ds[tt][h+j] = bf2f(vd[j]);
      zs[tt][h+j] = bf2f(vz[j]);
    }
  }
  for (int i = tid; i < CLEN*32; i += 256) {
    int tt = i >> 5, cq = i & 31;
    int t = t0 + tt;
    float v = (t < L_TOK) ? xdbl[(size_t)t*XDBL_N + 12 + cq] : 0.f;
    if (cq < 16) bs[tt][cq] = v;
    else cs[tt][cq-16] = v;
  }
  __syncthreads();

  float a2 = -expf(A_log[d*DS + n]) * 1.44269504088896340736f;
  float dpv = Dp[d];
#pragma unroll 4
  for (int tt = 0; tt < CLEN; ++tt) {
    float dv = ds[tt][dl], uu = us[tt][dl];
    float dA = exp2f(dv * a2);
    s = fmaf(dA, s, dv * bs[tt][n] * uu);
    float p = s * cs[tt][n];
    p += __shfl_xor(p, 1, 64);
    p += __shfl_xor(p, 2, 64);
    p += __shfl_xor(p, 4, 64);
    p += __shfl_xor(p, 8, 64);
    if (n == 0 && tt < nt) {
      float z = zs[tt][dl];
      float y = fmaf(uu, dpv, p);
      y *= z / (1.0f + expf(-z));
      yyb[(size_t)(t0 + tt)*DI + d] = f2bf(y);
    }
  }
}

// ---------------------------------------------------------------------------
// out projection: cur += yy(bf16) @ W_out^T, M=1569, N=192, K=384, split-K 4,
// atomicAdd residual into cur.
// ---------------------------------------------------------------------------
__global__ __launch_bounds__(256) void mgemm_kernel(
    const unsigned short* __restrict__ A, int lda,
    const float* __restrict__ B, int ldb,
    float* __restrict__ C, int ldc,
    int M, int N, int ksl) {
  __shared__ unsigned short As[64*40];
  __shared__ unsigned short Bs[64*40];
  int tid = threadIdx.x;
  int m0 = blockIdx.y * 64, n0 = blockIdx.x * 64;
  int kbase = blockIdx.z * ksl;
  int wave = tid >> 6, lane = tid & 63;
  int wr = wave >> 1, wc = wave & 1;
  int srow = tid >> 2;
  int skq  = (tid & 3) * 8;
  f32x4 acc[2][2];
#pragma unroll
  for (int i = 0; i < 2; ++i)
#pragma unroll
    for (int j = 0; j < 2; ++j) acc[i][j] = (f32x4){0.f,0.f,0.f,0.f};

  int am = m0 + srow;
  int bn = n0 + srow;
  bool a_ok = (am < M), b_ok = (bn < N);
  const unsigned short* ap = A + (size_t)am*lda + kbase + skq;
  const float* bp = B + (size_t)bn*ldb + kbase + skq;
  const float4 z4 = {0.f,0.f,0.f,0.f};
  const us8 z8 = {0,0,0,0,0,0,0,0};
  int l15 = lane & 15, lk = (lane >> 4) * 8;

  int nt = ksl >> 5;
  us8 av = a_ok ? *(const us8*)(ap) : z8;
  float4 b0 = b_ok ? *(const float4*)(bp)     : z4;
  float4 b1 = b_ok ? *(const float4*)(bp + 4) : z4;

  for (int i = 0; i < nt; ++i) {
    {
      short8 pb;
      pb[0]=f2bf(b0.x); pb[1]=f2bf(b0.y); pb[2]=f2bf(b0.z); pb[3]=f2bf(b0.w);
      pb[4]=f2bf(b1.x); pb[5]=f2bf(b1.y); pb[6]=f2bf(b1.z); pb[7]=f2bf(b1.w);
      *(us8*)&As[srow*40 + skq] = av;
      *(short8*)&Bs[srow*40 + skq] = pb;
    }
    __syncthreads();
    bool pf = (i + 1 < nt);
    int k0n = (i + 1) << 5;
    av = (pf && a_ok) ? *(const us8*)(ap + k0n) : z8;
    b0 = (pf && b_ok) ? *(const float4*)(bp + k0n)     : z4;
    b1 = (pf && b_ok) ? *(const float4*)(bp + k0n + 4) : z4;

    short8 af0 = *(const short8*)&As[(wr*32      + l15)*40 + lk];
    short8 af1 = *(const short8*)&As[(wr*32 + 16 + l15)*40 + lk];
    short8 bf0 = *(const short8*)&Bs[(wc*32      + l15)*40 + lk];
    short8 bf1 = *(const short8*)&Bs[(wc*32 + 16 + l15)*40 + lk];
    acc[0][0] = __builtin_amdgcn_mfma_f32_16x16x32_bf16(af0, bf0, acc[0][0], 0, 0, 0);
    acc[0][1] = __builtin_amdgcn_mfma_f32_16x16x32_bf16(af0, bf1, acc[0][1], 0, 0, 0);
    acc[1][0] = __builtin_amdgcn_mfma_f32_16x16x32_bf16(af1, bf0, acc[1][0], 0, 0, 0);
    acc[1][1] = __builtin_amdgcn_mfma_f32_16x16x32_bf16(af1, bf1, acc[1][1], 0, 0, 0);
    __syncthreads();
  }

#pragma unroll
  for (int r = 0; r < 2; ++r) {
#pragma unroll
    for (int c = 0; c < 2; ++c) {
      int col = n0 + wc*32 + c*16 + l15;
      if (col >= N) continue;
      int rowb = m0 + wr*32 + r*16 + (lane >> 4)*4;
#pragma unroll
      for (int j = 0; j < 4; ++j) {
        int row = rowb + j;
        if (row >= M) continue;
        atomicAdd(C + (size_t)row*ldc + col, acc[r][c][j]);
      }
    }
  }
}

// ---------------------------------------------------------------------------
extern "C" void kernel_launch(void* const* d_in, const int* in_sizes, int n_in,
                              void* d_out, int out_size, void* d_ws, size_t ws_size,
                              hipStream_t stream) {
  const float* x       = (const float*)d_in[0];
  const float* patch_w = (const float*)d_in[1];
  const float* patch_b = (const float*)d_in[2];
  const float* cls_tok = (const float*)d_in[3];
  const float* pos_emb = (const float*)d_in[4];
  const float* ln_g    = (const float*)d_in[5];
  const float* ln_b    = (const float*)d_in[6];
  const float* W_in    = (const float*)d_in[7];
  const float* Wc      = (const float*)d_in[8];
  const float* bc      = (const float*)d_in[9];
  const float* Wx      = (const float*)d_in[10];
  const float* W_dt    = (const float*)d_in[11];
  const float* b_dt    = (const float*)d_in[12];
  const float* A_log   = (const float*)d_in[13];
  const float* Dp      = (const float*)d_in[14];
  const float* W_out   = (const float*)d_in[15];
  const float* fn_g    = (const float*)d_in[16];
  const float* fn_b    = (const float*)d_in[17];

  float* ws = (float*)d_ws;
  float* cur   = ws;                                        // 1569*192 f32
  unsigned short* xzb = (unsigned short*)(cur + L_TOK*DM);  // 1569*768 bf16
  float* xdbl  = (float*)(xzb + L_TOK*2*DI);                // 1569*44  f32
  unsigned short* ucb  = (unsigned short*)(xdbl + L_TOK*XDBL_N); // 1569*384 bf16
  unsigned short* dltb = ucb  + L_TOK*DI;                   // 1569*384 bf16
  unsigned short* yyb  = dltb + L_TOK*DI;                   // 1569*384 bf16
  float* cP    = (float*)(yyb + L_TOK*DI);                  // 50*6144 f32
  float* cS    = cP + NCHUNK*DI*DS;

  init_kernel<<<(L_TOK*DM/4 + 255)/256, 256, 0, stream>>>(
      cls_tok, patch_b, pos_emb, cur);
  {
    dim3 grid(DM/64, (NPATCH + 63)/64, 4);
    patch_gemm<<<grid, 256, 0, stream>>>(x, patch_w, cur + DM);
  }

  for (int dep = 0; dep < DEPTH; ++dep) {
    const float* g     = ln_g  + dep*DM;
    const float* bb    = ln_b  + dep*DM;
    const float* Win_l = W_in  + (size_t)dep*2*DI*DM;
    const float* Wc_l  = Wc    + (size_t)dep*DI*DCONV;
    const float* bc_l  = bc    + (size_t)dep*DI;
    const float* Wx_l  = Wx    + (size_t)dep*XDBL_N*DI;
    const float* Wdt_l = W_dt  + (size_t)dep*DI*DTR;
    const float* bdt_l = b_dt  + (size_t)dep*DI;
    const float* Alog_l= A_log + (size_t)dep*DI*DS;
    const float* Dp_l  = Dp    + (size_t)dep*DI;
    const float* Wout_l= W_out + (size_t)dep*DM*DI;

    // xz = LN(cur) @ W_in^T (bf16 out; zeroes xdbl)
    {
      dim3 grid((2*DI)/64, (L_TOK + 63)/64);
      lnxz_kernel<<<grid, 256, 0, stream>>>(cur, g, bb, Win_l, xzb, xdbl);
    }
    // xdbl = silu(conv(u)) @ Wx^T, split-K 12; exports ucb (bf16)
    {
      dim3 grid(1, (L_TOK + 63)/64, 12);
      cgemm_kernel<<<grid, 256, 0, stream>>>(xzb, Wc_l, bc_l, Wx_l, xdbl, ucb);
    }
    // selective scan: local (p1, exports delta bf16) then carry+emit (p3)
    {
      dim3 g1(NDG, NCHUNK);
      scan_p1<<<g1, 256, 0, stream>>>(ucb, xdbl, Wdt_l, bdt_l, Alog_l, cP, cS, dltb);
      scan_p3<<<g1, 256, 0, stream>>>(ucb, dltb, xdbl, xzb, Alog_l, Dp_l, cP, cS, yyb);
    }
    // cur += yy @ W_out^T
    {
      dim3 grid(DM/64, (L_TOK + 63)/64, 4);
      mgemm_kernel<<<grid, 256, 0, stream>>>(yyb, DI, Wout_l, DI, cur, DM,
                                             L_TOK, DM, DI/4);
    }
  }

  ln_kernel<<<L_TOK, 64, 0, stream>>>(cur, (float*)d_out, fn_g, fn_b);
}

// Round 14
// 499.230 us; speedup vs baseline: 5.0384x; 1.0872x over previous
//
#include <hip/hip_runtime.h>
#include <hip/hip_bf16.h>
#include <math.h>

#define L_TOK 1569
#define DM 192
#define DI 384
#define DS 16
#define DTR 12
#define DCONV 4
#define XDBL_N (DTR + 2*DS)   // 44
#define DEPTH 8
#define NCHUNK 50
#define CLEN 32
#define NPATCH 1568
#define NDG 24                // scan d-groups (384/16)

typedef __attribute__((ext_vector_type(8))) short short8;
typedef __attribute__((ext_vector_type(8))) unsigned short us8;
typedef __attribute__((ext_vector_type(4))) float f32x4;

__device__ __forceinline__ unsigned short f2bf(float f) {
  unsigned int u = __float_as_uint(f);
  u += 0x7FFFu + ((u >> 16) & 1u);   // round-to-nearest-even
  return (unsigned short)(u >> 16);
}

__device__ __forceinline__ float bf2f(unsigned short h) {
  return __uint_as_float(((unsigned int)h) << 16);
}

// sizes (elements) of converted weight blocks
#define PW_N  (192*768)
#define WIN_N (DEPTH*2*DI*DM)
#define WX_N  (DEPTH*XDBL_N*DI)
#define WO_N  (DEPTH*DM*DI)

__device__ __forceinline__ void cv8(const float* __restrict__ s,
                                    unsigned short* __restrict__ d, int i) {
  float4 a = *(const float4*)(s + (size_t)i*8);
  float4 b = *(const float4*)(s + (size_t)i*8 + 4);
  us8 o;
  o[0]=f2bf(a.x); o[1]=f2bf(a.y); o[2]=f2bf(a.z); o[3]=f2bf(a.w);
  o[4]=f2bf(b.x); o[5]=f2bf(b.y); o[6]=f2bf(b.z); o[7]=f2bf(b.w);
  *(us8*)(d + (size_t)i*8) = o;
}

// ---------------------------------------------------------------------------
// init: cur[tok][e] = pos + (tok==0 ? cls : patch_b); also converts all MFMA
// B-operand weights to bf16 (one-time, stream-ordered before first use).
// ---------------------------------------------------------------------------
__global__ __launch_bounds__(256) void init_kernel(
    const float* __restrict__ cls, const float* __restrict__ pb,
    const float* __restrict__ pos, float* __restrict__ curp,
    const float* __restrict__ pw,  const float* __restrict__ wi,
    const float* __restrict__ wx,  const float* __restrict__ wo,
    unsigned short* __restrict__ pwb, unsigned short* __restrict__ winb,
    unsigned short* __restrict__ wxb, unsigned short* __restrict__ wob) {
  int tid0 = blockIdx.x * 256 + threadIdx.x;
  int NT = gridDim.x * 256;
  const int initN = (L_TOK * DM) / 4;
  for (int gid = tid0; gid < initN; gid += NT) {
    int e4 = gid * 4;
    int tok = e4 / DM;
    int col = e4 % DM;
    float4 pv = *(const float4*)(pos + e4);
    float4 av = (tok == 0) ? *(const float4*)(cls + col)
                           : *(const float4*)(pb + col);
    float4 o = {pv.x + av.x, pv.y + av.y, pv.z + av.z, pv.w + av.w};
    *(float4*)(curp + e4) = o;
  }
  for (int i = tid0; i < PW_N/8;  i += NT) cv8(pw, pwb, i);
  for (int i = tid0; i < WIN_N/8; i += NT) cv8(wi, winb, i);
  for (int i = tid0; i < WX_N/8;  i += NT) cv8(wx, wxb, i);
  for (int i = tid0; i < WO_N/8;  i += NT) cv8(wo, wob, i);
}

// ---------------------------------------------------------------------------
// Final LayerNorm. One wave per token.
// ---------------------------------------------------------------------------
__global__ __launch_bounds__(64) void ln_kernel(
    const float* __restrict__ in, float* __restrict__ out,
    const float* __restrict__ g, const float* __restrict__ b) {
  int tokn = blockIdx.x;
  int lane = threadIdx.x;
  const float* row = in + (size_t)tokn*DM;
  float x0 = row[lane], x1 = row[lane+64], x2 = row[lane+128];
  float s = x0 + x1 + x2;
  float s2 = x0*x0 + x1*x1 + x2*x2;
#pragma unroll
  for (int off = 1; off < 64; off <<= 1) {
    s  += __shfl_xor(s,  off, 64);
    s2 += __shfl_xor(s2, off, 64);
  }
  float m = s * (1.0f/192.0f);
  float v = s2 * (1.0f/192.0f) - m*m;
  float rs = rsqrtf(v + 1e-5f);
  float* orow = out + (size_t)tokn*DM;
  orow[lane]     = (x0 - m)*rs*g[lane]     + b[lane];
  orow[lane+64]  = (x1 - m)*rs*g[lane+64]  + b[lane+64];
  orow[lane+128] = (x2 - m)*rs*g[lane+128] + b[lane+128];
}

// ---------------------------------------------------------------------------
// Patch GEMM, im2col fused into A-staging, bf16 weights:
// cur[1..][:] += X_patch @ patch_w^T. M=1568, N=192, K=768, split-K 4.
// ---------------------------------------------------------------------------
__device__ __forceinline__ float4 ldx4(const float* __restrict__ x,
                                       int pt, int hh, int w, int k) {
  int c = k >> 8, p = (k >> 4) & 15, q = k & 15;
  return *(const float4*)(x + ((size_t)(c*8 + pt)*224 + hh*16 + p)*224
                            + w*16 + q);
}

__global__ __launch_bounds__(256) void patch_gemm(
    const float* __restrict__ x, const unsigned short* __restrict__ pw,
    float* __restrict__ C) {
  __shared__ unsigned short As[64*40];
  __shared__ unsigned short Bs[64*40];
  int tid = threadIdx.x;
  int m0 = blockIdx.y * 64, n0 = blockIdx.x * 64;
  int kbase = blockIdx.z * 192;
  int wave = tid >> 6, lane = tid & 63;
  int wr = wave >> 1, wc = wave & 1;
  int srow = tid >> 2;
  int skq  = (tid & 3) * 8;
  f32x4 acc[2][2];
#pragma unroll
  for (int i = 0; i < 2; ++i)
#pragma unroll
    for (int j = 0; j < 2; ++j) acc[i][j] = (f32x4){0.f,0.f,0.f,0.f};

  int am = m0 + srow;
  bool a_ok = (am < NPATCH);
  int am_s = a_ok ? am : 0;
  int pt = am_s / 196, hw = am_s % 196, hh = hw / 14, w = hw % 14;
  int bn = n0 + srow;
  const unsigned short* bp = pw + (size_t)bn*768 + kbase + skq;
  const float4 z4 = {0.f,0.f,0.f,0.f};
  const us8 z8 = {0,0,0,0,0,0,0,0};
  int l15 = lane & 15, lk = (lane >> 4) * 8;

  const int nt = 6;   // 192/32
  float4 a0 = a_ok ? ldx4(x, pt, hh, w, kbase + skq)     : z4;
  float4 a1 = a_ok ? ldx4(x, pt, hh, w, kbase + skq + 4) : z4;
  us8 bv = *(const us8*)(bp);

  for (int i = 0; i < nt; ++i) {
    {
      short8 pa;
      pa[0]=f2bf(a0.x); pa[1]=f2bf(a0.y); pa[2]=f2bf(a0.z); pa[3]=f2bf(a0.w);
      pa[4]=f2bf(a1.x); pa[5]=f2bf(a1.y); pa[6]=f2bf(a1.z); pa[7]=f2bf(a1.w);
      *(short8*)&As[srow*40 + skq] = pa;
      *(us8*)&Bs[srow*40 + skq] = bv;
    }
    __syncthreads();
    bool pf = (i + 1 < nt);
    int kn = kbase + ((i + 1) << 5) + skq;
    a0 = (pf && a_ok) ? ldx4(x, pt, hh, w, kn)     : z4;
    a1 = (pf && a_ok) ? ldx4(x, pt, hh, w, kn + 4) : z4;
    bv = pf ? *(const us8*)(bp + ((i+1)<<5)) : z8;

    short8 af0 = *(const short8*)&As[(wr*32      + l15)*40 + lk];
    short8 af1 = *(const short8*)&As[(wr*32 + 16 + l15)*40 + lk];
    short8 bf0 = *(const short8*)&Bs[(wc*32      + l15)*40 + lk];
    short8 bf1 = *(const short8*)&Bs[(wc*32 + 16 + l15)*40 + lk];
    acc[0][0] = __builtin_amdgcn_mfma_f32_16x16x32_bf16(af0, bf0, acc[0][0], 0, 0, 0);
    acc[0][1] = __builtin_amdgcn_mfma_f32_16x16x32_bf16(af0, bf1, acc[0][1], 0, 0, 0);
    acc[1][0] = __builtin_amdgcn_mfma_f32_16x16x32_bf16(af1, bf0, acc[1][0], 0, 0, 0);
    acc[1][1] = __builtin_amdgcn_mfma_f32_16x16x32_bf16(af1, bf1, acc[1][1], 0, 0, 0);
    __syncthreads();
  }

#pragma unroll
  for (int r = 0; r < 2; ++r) {
#pragma unroll
    for (int c = 0; c < 2; ++c) {
      int col = n0 + wc*32 + c*16 + l15;
      int rowb = m0 + wr*32 + r*16 + (lane >> 4)*4;
#pragma unroll
      for (int j = 0; j < 4; ++j) {
        int row = rowb + j;
        if (row < NPATCH)
          atomicAdd(C + (size_t)row*DM + col, acc[r][c][j]);
      }
    }
  }
}

// ---------------------------------------------------------------------------
// Fused LN + xz GEMM (bf16 W_in); output xz bf16. Zeroes xdbl (bx==0).
// ---------------------------------------------------------------------------
__global__ __launch_bounds__(256) void lnxz_kernel(
    const float* __restrict__ cur, const float* __restrict__ g,
    const float* __restrict__ b, const unsigned short* __restrict__ W,
    unsigned short* __restrict__ xzb, float* __restrict__ xdbl_z) {
  __shared__ unsigned short As[64][200];
  __shared__ unsigned short Bs[64][200];
  __shared__ float gs[192], bs2[192];
  int tid = threadIdx.x;
  int m0 = blockIdx.y * 64, n0 = blockIdx.x * 64;
  int wave = tid >> 6, lane = tid & 63;
  int wr = wave >> 1, wc = wave & 1;
  int l15 = lane & 15, lk = (lane >> 4) * 8;

  for (int i = tid; i < 192; i += 256) { gs[i] = g[i]; bs2[i] = b[i]; }

  if (blockIdx.x == 0) {
    for (int i = tid; i < 64*11; i += 256) {
      int r = i / 11, q = i % 11;
      int row = m0 + r;
      if (row < L_TOK) {
        float4 z = {0.f,0.f,0.f,0.f};
        *(float4*)(xdbl_z + (size_t)row*XDBL_N + q*4) = z;
      }
    }
  }

  int r = tid >> 2, c0 = (tid & 3) * 48;
  float v[48];
  {
    int row = m0 + r;
    if (row < L_TOK) {
      const float* rp = cur + (size_t)row*DM + c0;
#pragma unroll
      for (int j = 0; j < 12; ++j) {
        float4 t4 = *(const float4*)(rp + j*4);
        v[j*4+0]=t4.x; v[j*4+1]=t4.y; v[j*4+2]=t4.z; v[j*4+3]=t4.w;
      }
    } else {
#pragma unroll
      for (int j = 0; j < 48; ++j) v[j] = 0.f;
    }
  }
  float s = 0.f, s2 = 0.f;
#pragma unroll
  for (int j = 0; j < 48; ++j) { s += v[j]; s2 += v[j]*v[j]; }
  s  += __shfl_xor(s, 1, 64); s2 += __shfl_xor(s2, 1, 64);
  s  += __shfl_xor(s, 2, 64); s2 += __shfl_xor(s2, 2, 64);
  float mu = s * (1.0f/192.0f);
  float var = s2 * (1.0f/192.0f) - mu*mu;
  float rsd = rsqrtf(var + 1e-5f);

  __syncthreads();
#pragma unroll
  for (int j = 0; j < 48; ++j) {
    int k = c0 + j;
    As[r][k] = f2bf((v[j] - mu)*rsd*gs[k] + bs2[k]);
  }
  {
    const unsigned short* rp = W + (size_t)(n0 + r)*DM + c0;
#pragma unroll
    for (int j = 0; j < 6; ++j)
      *(us8*)&Bs[r][c0 + j*8] = *(const us8*)(rp + j*8);
  }
  __syncthreads();

  f32x4 acc[2][2];
#pragma unroll
  for (int i = 0; i < 2; ++i)
#pragma unroll
    for (int j = 0; j < 2; ++j) acc[i][j] = (f32x4){0.f,0.f,0.f,0.f};

#pragma unroll
  for (int kk = 0; kk < 6; ++kk) {
    short8 af0 = *(const short8*)&As[wr*32      + l15][kk*32 + lk];
    short8 af1 = *(const short8*)&As[wr*32 + 16 + l15][kk*32 + lk];
    short8 bf0 = *(const short8*)&Bs[wc*32      + l15][kk*32 + lk];
    short8 bf1 = *(const short8*)&Bs[wc*32 + 16 + l15][kk*32 + lk];
    acc[0][0] = __builtin_amdgcn_mfma_f32_16x16x32_bf16(af0, bf0, acc[0][0], 0, 0, 0);
    acc[0][1] = __builtin_amdgcn_mfma_f32_16x16x32_bf16(af0, bf1, acc[0][1], 0, 0, 0);
    acc[1][0] = __builtin_amdgcn_mfma_f32_16x16x32_bf16(af1, bf0, acc[1][0], 0, 0, 0);
    acc[1][1] = __builtin_amdgcn_mfma_f32_16x16x32_bf16(af1, bf1, acc[1][1], 0, 0, 0);
  }

#pragma unroll
  for (int rr = 0; rr < 2; ++rr) {
#pragma unroll
    for (int cc = 0; cc < 2; ++cc) {
      int col = n0 + wc*32 + cc*16 + l15;
      int rowb = m0 + wr*32 + rr*16 + (lane >> 4)*4;
#pragma unroll
      for (int j = 0; j < 4; ++j) {
        int row = rowb + j;
        if (row < L_TOK)
          xzb[(size_t)row*(2*DI) + col] = f2bf(acc[rr][cc][j]);
      }
    }
  }
}

// ---------------------------------------------------------------------------
// xdbl GEMM, conv+SiLU fused in A-staging; bf16 Wx; split-K 12 (one k-step).
// Exports u (bf16) to ucb. xdbl (f32) zero-init by lnxz. grid = (1, 25, 12).
// ---------------------------------------------------------------------------
__global__ __launch_bounds__(256) void cgemm_kernel(
    const unsigned short* __restrict__ xzb,
    const float* __restrict__ Wc, const float* __restrict__ bc,
    const unsigned short* __restrict__ B, float* __restrict__ C,
    unsigned short* __restrict__ ucb) {
  __shared__ unsigned short As[64*40];
  __shared__ unsigned short Bs[64*40];
  __shared__ float wcs[32][4];
  __shared__ float bcs[32];
  const int M = L_TOK, N = XDBL_N;
  int tid = threadIdx.x;
  int m0 = blockIdx.y * 64;
  int kbase = blockIdx.z * 32;
  int wave = tid >> 6, lane = tid & 63;
  int wr = wave >> 1, wcq = wave & 1;
  int srow = tid >> 2;
  int skq  = (tid & 3) * 8;
  if (tid < 32) {
    *(float4*)wcs[tid] = *(const float4*)(Wc + (size_t)(kbase + tid)*4);
    bcs[tid] = bc[kbase + tid];
  }

  int t = m0 + srow;
  bool a_ok = (t < M);
  bool b_ok = (srow < N);
  const unsigned short* bp = B + (size_t)srow*DI + kbase + skq;
  const us8 z8 = {0,0,0,0,0,0,0,0};
  int l15 = lane & 15, lk = (lane >> 4) * 8;
  int cg = kbase + skq;

  us8 tap[4];
#pragma unroll
  for (int j = 0; j < 4; ++j) {
    int ts = t - 3 + j;
    tap[j] = (a_ok && ts >= 0)
               ? *(const us8*)(xzb + (size_t)ts*(2*DI) + cg) : z8;
  }
  us8 bv = b_ok ? *(const us8*)(bp) : z8;
  __syncthreads();   // wcs/bcs ready

  short8 pa;
#pragma unroll
  for (int c = 0; c < 8; ++c) {
    float u = bcs[skq + c];
#pragma unroll
    for (int j = 0; j < 4; ++j)
      u = fmaf(bf2f(tap[j][c]), wcs[skq + c][j], u);
    u = u / (1.0f + expf(-u));
    pa[c] = (short)f2bf(u);
  }
  if (a_ok)
    *(short8*)(ucb + (size_t)t*DI + cg) = pa;
  *(short8*)&As[srow*40 + skq] = pa;
  *(us8*)&Bs[srow*40 + skq] = bv;
  __syncthreads();

  f32x4 acc[2][2];
#pragma unroll
  for (int i = 0; i < 2; ++i)
#pragma unroll
    for (int j = 0; j < 2; ++j) acc[i][j] = (f32x4){0.f,0.f,0.f,0.f};
  short8 af0 = *(const short8*)&As[(wr*32      + l15)*40 + lk];
  short8 af1 = *(const short8*)&As[(wr*32 + 16 + l15)*40 + lk];
  short8 bf0 = *(const short8*)&Bs[(wcq*32      + l15)*40 + lk];
  short8 bf1 = *(const short8*)&Bs[(wcq*32 + 16 + l15)*40 + lk];
  acc[0][0] = __builtin_amdgcn_mfma_f32_16x16x32_bf16(af0, bf0, acc[0][0], 0, 0, 0);
  acc[0][1] = __builtin_amdgcn_mfma_f32_16x16x32_bf16(af0, bf1, acc[0][1], 0, 0, 0);
  acc[1][0] = __builtin_amdgcn_mfma_f32_16x16x32_bf16(af1, bf0, acc[1][0], 0, 0, 0);
  acc[1][1] = __builtin_amdgcn_mfma_f32_16x16x32_bf16(af1, bf1, acc[1][1], 0, 0, 0);

#pragma unroll
  for (int r = 0; r < 2; ++r) {
#pragma unroll
    for (int c = 0; c < 2; ++c) {
      int col = wcq*32 + c*16 + l15;
      if (col >= N) continue;
      int rowb = m0 + wr*32 + r*16 + (lane >> 4)*4;
#pragma unroll
      for (int j = 0; j < 4; ++j) {
        int row = rowb + j;
        if (row >= M) continue;
        atomicAdd(C + (size_t)row*XDBL_N + col, acc[r][c][j]);
      }
    }
  }
}

// ---------------------------------------------------------------------------
// scan_p1: per-chunk local scan from zero state (CLEN=32). Exports delta bf16.
// grid = (NDG, NCHUNK) = (24, 50), 256 thr = 16d x 16n.
// ---------------------------------------------------------------------------
__global__ __launch_bounds__(256) void scan_p1(
    const unsigned short* __restrict__ ucb, const float* __restrict__ xdbl,
    const float* __restrict__ W_dt, const float* __restrict__ b_dt,
    const float* __restrict__ A_log,
    float* __restrict__ cP, float* __restrict__ cS,
    unsigned short* __restrict__ dltb) {
  __shared__ float us[CLEN][16], ds[CLEN][16], bs[CLEN][16];
  __shared__ float xd12[CLEN][12], wdt[16][12], bds[16];
  int tid = threadIdx.x;
  int dl = tid >> 4, n = tid & 15;
  int d0 = blockIdx.x * 16;
  int t0 = blockIdx.y * CLEN;
  const us8 z8 = {0,0,0,0,0,0,0,0};
  const float4 z4 = {0.f,0.f,0.f,0.f};

  for (int i = tid; i < CLEN*2; i += 256) {
    int tt = i >> 1, h = (i & 1) * 8;
    int t = t0 + tt;
    us8 v = (t < L_TOK) ? *(const us8*)(ucb + (size_t)t*DI + d0 + h) : z8;
#pragma unroll
    for (int j = 0; j < 8; ++j) us[tt][h+j] = bf2f(v[j]);
  }
  for (int i = tid; i < CLEN*7; i += 256) {
    int tt = i / 7, q = i % 7;
    int t = t0 + tt;
    float4 v = (t < L_TOK) ? *(const float4*)(xdbl + (size_t)t*XDBL_N + q*4) : z4;
    if (q < 3) {
      xd12[tt][q*4+0]=v.x; xd12[tt][q*4+1]=v.y;
      xd12[tt][q*4+2]=v.z; xd12[tt][q*4+3]=v.w;
    } else {
      int c = (q-3)*4;
      bs[tt][c+0]=v.x; bs[tt][c+1]=v.y; bs[tt][c+2]=v.z; bs[tt][c+3]=v.w;
    }
  }
  if (tid < 192) wdt[tid/12][tid%12] = W_dt[(d0 + tid/12)*DTR + tid%12];
  if (tid < 16)  bds[tid] = b_dt[d0+tid];
  __syncthreads();
  for (int i = tid; i < CLEN*16; i += 256) {
    int tt = i >> 4, dd = i & 15;
    int t = t0 + tt;
    float v = 0.0f;
    if (t < L_TOK) {
      v = bds[dd];
#pragma unroll
      for (int r = 0; r < 12; ++r) v = fmaf(xd12[tt][r], wdt[dd][r], v);
      v = (v > 20.0f) ? v : log1pf(expf(v));
      unsigned short hb = f2bf(v);
      dltb[(size_t)t*DI + d0 + dd] = hb;
      v = bf2f(hb);   // use rounded value so p1/p3 scans agree exactly
    }
    ds[tt][dd] = v;
  }
  __syncthreads();

  int d = d0 + dl;
  float a2 = -expf(A_log[d*DS + n]) * 1.44269504088896340736f;
  float s = 0.0f, P = 1.0f;
#pragma unroll 4
  for (int tt = 0; tt < CLEN; ++tt) {
    float dv = ds[tt][dl];
    float dA = exp2f(dv * a2);
    s = fmaf(dA, s, dv * bs[tt][n] * us[tt][dl]);
    P *= dA;
  }
  int o = (blockIdx.y * DI + d) * DS + n;
  cP[o] = P;
  cS[o] = s;
}

// ---------------------------------------------------------------------------
// scan_p3: carry-in combine over preceding chunks, re-scan, emit y (bf16).
// grid = (NDG, NCHUNK) = (24, 50), 256 thr.
// ---------------------------------------------------------------------------
__global__ __launch_bounds__(256) void scan_p3(
    const unsigned short* __restrict__ ucb,
    const unsigned short* __restrict__ dltb,
    const float* __restrict__ xdbl, const unsigned short* __restrict__ xzb,
    const float* __restrict__ A_log, const float* __restrict__ Dp,
    const float* __restrict__ cP, const float* __restrict__ cS,
    unsigned short* __restrict__ yyb) {
  __shared__ float us[CLEN][16], ds[CLEN][16], bs[CLEN][16];
  __shared__ float cs[CLEN][16], zs[CLEN][16];
  int tid = threadIdx.x;
  int dl = tid >> 4, n = tid & 15;
  int d0 = blockIdx.x * 16;
  int cidx = blockIdx.y;
  int t0 = cidx * CLEN;
  int nt = min(CLEN, L_TOK - t0);
  int d = d0 + dl;
  const us8 z8 = {0,0,0,0,0,0,0,0};
  const float4 z4 = {0.f,0.f,0.f,0.f};

  float s = 0.0f;
  {
    int oo = d * DS + n;
    for (int c2 = 0; c2 < cidx; ++c2)
      s = fmaf(cP[(size_t)c2*(DI*DS) + oo], s, cS[(size_t)c2*(DI*DS) + oo]);
  }

  for (int i = tid; i < CLEN*2; i += 256) {
    int tt = i >> 1, h = (i & 1) * 8;
    int t = t0 + tt;
    bool ok = (t < L_TOK);
    us8 vu = ok ? *(const us8*)(ucb  + (size_t)t*DI + d0 + h) : z8;
    us8 vd = ok ? *(const us8*)(dltb + (size_t)t*DI + d0 + h) : z8;
    us8 vz = ok ? *(const us8*)(xzb  + (size_t)t*(2*DI) + DI + d0 + h) : z8;
#pragma unroll
    for (int j = 0; j < 8; ++j) {
      us[tt][h+j] = bf2f(vu[j]);
      ds[tt][h+j] = bf2f(vd[j]);
      zs[tt][h+j] = bf2f(vz[j]);
    }
  }
  for (int i = tid; i < CLEN*8; i += 256) {
    int tt = i >> 3, q = i & 7;
    int t = t0 + tt;
    float4 v = (t < L_TOK)
                 ? *(const float4*)(xdbl + (size_t)t*XDBL_N + 12 + q*4) : z4;
    if (q < 4) {
      int c = q*4;
      bs[tt][c+0]=v.x; bs[tt][c+1]=v.y; bs[tt][c+2]=v.z; bs[tt][c+3]=v.w;
    } else {
      int c = (q-4)*4;
      cs[tt][c+0]=v.x; cs[tt][c+1]=v.y; cs[tt][c+2]=v.z; cs[tt][c+3]=v.w;
    }
  }
  __syncthreads();

  float a2 = -expf(A_log[d*DS + n]) * 1.44269504088896340736f;
  float dpv = Dp[d];
#pragma unroll 4
  for (int tt = 0; tt < CLEN; ++tt) {
    float dv = ds[tt][dl], uu = us[tt][dl];
    float dA = exp2f(dv * a2);
    s = fmaf(dA, s, dv * bs[tt][n] * uu);
    float p = s * cs[tt][n];
    p += __shfl_xor(p, 1, 64);
    p += __shfl_xor(p, 2, 64);
    p += __shfl_xor(p, 4, 64);
    p += __shfl_xor(p, 8, 64);
    if (n == 0 && tt < nt) {
      float z = zs[tt][dl];
      float y = fmaf(uu, dpv, p);
      y *= z / (1.0f + expf(-z));
      yyb[(size_t)(t0 + tt)*DI + d] = f2bf(y);
    }
  }
}

// ---------------------------------------------------------------------------
// out projection: cur += yy(bf16) @ W_out(bf16)^T, split-K 4, atomicAdd.
// ---------------------------------------------------------------------------
__global__ __launch_bounds__(256) void mgemm_kernel(
    const unsigned short* __restrict__ A, int lda,
    const unsigned short* __restrict__ B, int ldb,
    float* __restrict__ C, int ldc,
    int M, int N, int ksl) {
  __shared__ unsigned short As[64*40];
  __shared__ unsigned short Bs[64*40];
  int tid = threadIdx.x;
  int m0 = blockIdx.y * 64, n0 = blockIdx.x * 64;
  int kbase = blockIdx.z * ksl;
  int wave = tid >> 6, lane = tid & 63;
  int wr = wave >> 1, wc = wave & 1;
  int srow = tid >> 2;
  int skq  = (tid & 3) * 8;
  f32x4 acc[2][2];
#pragma unroll
  for (int i = 0; i < 2; ++i)
#pragma unroll
    for (int j = 0; j < 2; ++j) acc[i][j] = (f32x4){0.f,0.f,0.f,0.f};

  int am = m0 + srow;
  int bn = n0 + srow;
  bool a_ok = (am < M), b_ok = (bn < N);
  const unsigned short* ap = A + (size_t)am*lda + kbase + skq;
  const unsigned short* bp = B + (size_t)bn*ldb + kbase + skq;
  const us8 z8 = {0,0,0,0,0,0,0,0};
  int l15 = lane & 15, lk = (lane >> 4) * 8;

  int nt = ksl >> 5;
  us8 av = a_ok ? *(const us8*)(ap) : z8;
  us8 bv = b_ok ? *(const us8*)(bp) : z8;

  for (int i = 0; i < nt; ++i) {
    *(us8*)&As[srow*40 + skq] = av;
    *(us8*)&Bs[srow*40 + skq] = bv;
    __syncthreads();
    bool pf = (i + 1 < nt);
    int k0n = (i + 1) << 5;
    av = (pf && a_ok) ? *(const us8*)(ap + k0n) : z8;
    bv = (pf && b_ok) ? *(const us8*)(bp + k0n) : z8;

    short8 af0 = *(const short8*)&As[(wr*32      + l15)*40 + lk];
    short8 af1 = *(const short8*)&As[(wr*32 + 16 + l15)*40 + lk];
    short8 bf0 = *(const short8*)&Bs[(wc*32      + l15)*40 + lk];
    short8 bf1 = *(const short8*)&Bs[(wc*32 + 16 + l15)*40 + lk];
    acc[0][0] = __builtin_amdgcn_mfma_f32_16x16x32_bf16(af0, bf0, acc[0][0], 0, 0, 0);
    acc[0][1] = __builtin_amdgcn_mfma_f32_16x16x32_bf16(af0, bf1, acc[0][1], 0, 0, 0);
    acc[1][0] = __builtin_amdgcn_mfma_f32_16x16x32_bf16(af1, bf0, acc[1][0], 0, 0, 0);
    acc[1][1] = __builtin_amdgcn_mfma_f32_16x16x32_bf16(af1, bf1, acc[1][1], 0, 0, 0);
    __syncthreads();
  }

#pragma unroll
  for (int r = 0; r < 2; ++r) {
#pragma unroll
    for (int c = 0; c < 2; ++c) {
      int col = n0 + wc*32 + c*16 + l15;
      if (col >= N) continue;
      int rowb = m0 + wr*32 + r*16 + (lane >> 4)*4;
#pragma unroll
      for (int j = 0; j < 4; ++j) {
        int row = rowb + j;
        if (row >= M) continue;
        atomicAdd(C + (size_t)row*ldc + col, acc[r][c][j]);
      }
    }
  }
}

// ---------------------------------------------------------------------------
extern "C" void kernel_launch(void* const* d_in, const int* in_sizes, int n_in,
                              void* d_out, int out_size, void* d_ws, size_t ws_size,
                              hipStream_t stream) {
  const float* x       = (const float*)d_in[0];
  const float* patch_w = (const float*)d_in[1];
  const float* patch_b = (const float*)d_in[2];
  const float* cls_tok = (const float*)d_in[3];
  const float* pos_emb = (const float*)d_in[4];
  const float* ln_g    = (const float*)d_in[5];
  const float* ln_b    = (const float*)d_in[6];
  const float* W_in    = (const float*)d_in[7];
  const float* Wc      = (const float*)d_in[8];
  const float* bc      = (const float*)d_in[9];
  const float* Wx      = (const float*)d_in[10];
  const float* W_dt    = (const float*)d_in[11];
  const float* b_dt    = (const float*)d_in[12];
  const float* A_log   = (const float*)d_in[13];
  const float* Dp      = (const float*)d_in[14];
  const float* W_out   = (const float*)d_in[15];
  const float* fn_g    = (const float*)d_in[16];
  const float* fn_b    = (const float*)d_in[17];

  float* ws = (float*)d_ws;
  float* cur   = ws;                                        // 1569*192 f32
  unsigned short* xzb = (unsigned short*)(cur + L_TOK*DM);  // 1569*768 bf16
  float* xdbl  = (float*)(xzb + L_TOK*2*DI);                // 1569*44  f32
  unsigned short* ucb  = (unsigned short*)(xdbl + L_TOK*XDBL_N); // bf16
  unsigned short* dltb = ucb  + L_TOK*DI;                   // bf16
  unsigned short* yyb  = dltb + L_TOK*DI;                   // bf16
  float* cP    = (float*)(yyb + L_TOK*DI);                  // 50*6144 f32
  float* cS    = cP + NCHUNK*DI*DS;
  unsigned short* pwb  = (unsigned short*)(cS + NCHUNK*DI*DS);
  unsigned short* winb = pwb  + PW_N;
  unsigned short* wxb  = winb + WIN_N;
  unsigned short* wob  = wxb  + WX_N;

  init_kernel<<<1024, 256, 0, stream>>>(
      cls_tok, patch_b, pos_emb, cur,
      patch_w, W_in, Wx, W_out, pwb, winb, wxb, wob);
  {
    dim3 grid(DM/64, (NPATCH + 63)/64, 4);
    patch_gemm<<<grid, 256, 0, stream>>>(x, pwb, cur + DM);
  }

  for (int dep = 0; dep < DEPTH; ++dep) {
    const float* g     = ln_g  + dep*DM;
    const float* bb    = ln_b  + dep*DM;
    const unsigned short* Win_l = winb + (size_t)dep*2*DI*DM;
    const float* Wc_l  = Wc    + (size_t)dep*DI*DCONV;
    const float* bc_l  = bc    + (size_t)dep*DI;
    const unsigned short* Wx_l  = wxb + (size_t)dep*XDBL_N*DI;
    const float* Wdt_l = W_dt  + (size_t)dep*DI*DTR;
    const float* bdt_l = b_dt  + (size_t)dep*DI;
    const float* Alog_l= A_log + (size_t)dep*DI*DS;
    const float* Dp_l  = Dp    + (size_t)dep*DI;
    const unsigned short* Wout_l= wob + (size_t)dep*DM*DI;

    // xz = LN(cur) @ W_in^T (bf16 out; zeroes xdbl)
    {
      dim3 grid((2*DI)/64, (L_TOK + 63)/64);
      lnxz_kernel<<<grid, 256, 0, stream>>>(cur, g, bb, Win_l, xzb, xdbl);
    }
    // xdbl = silu(conv(u)) @ Wx^T, split-K 12; exports ucb (bf16)
    {
      dim3 grid(1, (L_TOK + 63)/64, 12);
      cgemm_kernel<<<grid, 256, 0, stream>>>(xzb, Wc_l, bc_l, Wx_l, xdbl, ucb);
    }
    // selective scan: local (p1, exports delta bf16) then carry+emit (p3)
    {
      dim3 g1(NDG, NCHUNK);
      scan_p1<<<g1, 256, 0, stream>>>(ucb, xdbl, Wdt_l, bdt_l, Alog_l, cP, cS, dltb);
      scan_p3<<<g1, 256, 0, stream>>>(ucb, dltb, xdbl, xzb, Alog_l, Dp_l, cP, cS, yyb);
    }
    // cur += yy @ W_out^T
    {
      dim3 grid(DM/64, (L_TOK + 63)/64, 4);
      mgemm_kernel<<<grid, 256, 0, stream>>>(yyb, DI, Wout_l, DI, cur, DM,
                                             L_TOK, DM, DI/4);
    }
  }

  ln_kernel<<<L_TOK, 64, 0, stream>>>(cur, (float*)d_out, fn_g, fn_b);
}

// Round 15
// 474.547 us; speedup vs baseline: 5.3005x; 1.0520x over previous
//
#include <hip/hip_runtime.h>
#include <hip/hip_bf16.h>
#include <math.h>

#define L_TOK 1569
#define DM 192
#define DI 384
#define DS 16
#define DTR 12
#define DCONV 4
#define XDBL_N (DTR + 2*DS)   // 44
#define DEPTH 8
#define NCHUNK 50
#define CLEN 32
#define NPATCH 1568
#define NDG 24                // scan d-groups (384/16)

typedef __attribute__((ext_vector_type(8))) short short8;
typedef __attribute__((ext_vector_type(8))) unsigned short us8;
typedef __attribute__((ext_vector_type(4))) float f32x4;

__device__ __forceinline__ unsigned short f2bf(float f) {
  unsigned int u = __float_as_uint(f);
  u += 0x7FFFu + ((u >> 16) & 1u);   // round-to-nearest-even
  return (unsigned short)(u >> 16);
}

__device__ __forceinline__ float bf2f(unsigned short h) {
  return __uint_as_float(((unsigned int)h) << 16);
}

// sizes (elements) of converted weight blocks
#define PW_N  (192*768)
#define WIN_N (DEPTH*2*DI*DM)
#define WX_N  (DEPTH*XDBL_N*DI)
#define WO_N  (DEPTH*DM*DI)

__device__ __forceinline__ void cv8(const float* __restrict__ s,
                                    unsigned short* __restrict__ d, int i) {
  float4 a = *(const float4*)(s + (size_t)i*8);
  float4 b = *(const float4*)(s + (size_t)i*8 + 4);
  us8 o;
  o[0]=f2bf(a.x); o[1]=f2bf(a.y); o[2]=f2bf(a.z); o[3]=f2bf(a.w);
  o[4]=f2bf(b.x); o[5]=f2bf(b.y); o[6]=f2bf(b.z); o[7]=f2bf(b.w);
  *(us8*)(d + (size_t)i*8) = o;
}

// ---------------------------------------------------------------------------
// init: cur[tok][e] = pos + (tok==0 ? cls : patch_b); also converts all MFMA
// B-operand weights to bf16 (one-time, stream-ordered before first use).
// ---------------------------------------------------------------------------
__global__ __launch_bounds__(256) void init_kernel(
    const float* __restrict__ cls, const float* __restrict__ pb,
    const float* __restrict__ pos, float* __restrict__ curp,
    const float* __restrict__ pw,  const float* __restrict__ wi,
    const float* __restrict__ wx,  const float* __restrict__ wo,
    unsigned short* __restrict__ pwb, unsigned short* __restrict__ winb,
    unsigned short* __restrict__ wxb, unsigned short* __restrict__ wob) {
  int tid0 = blockIdx.x * 256 + threadIdx.x;
  int NT = gridDim.x * 256;
  const int initN = (L_TOK * DM) / 4;
  for (int gid = tid0; gid < initN; gid += NT) {
    int e4 = gid * 4;
    int tok = e4 / DM;
    int col = e4 % DM;
    float4 pv = *(const float4*)(pos + e4);
    float4 av = (tok == 0) ? *(const float4*)(cls + col)
                           : *(const float4*)(pb + col);
    float4 o = {pv.x + av.x, pv.y + av.y, pv.z + av.z, pv.w + av.w};
    *(float4*)(curp + e4) = o;
  }
  for (int i = tid0; i < PW_N/8;  i += NT) cv8(pw, pwb, i);
  for (int i = tid0; i < WIN_N/8; i += NT) cv8(wi, winb, i);
  for (int i = tid0; i < WX_N/8;  i += NT) cv8(wx, wxb, i);
  for (int i = tid0; i < WO_N/8;  i += NT) cv8(wo, wob, i);
}

// ---------------------------------------------------------------------------
// Final LayerNorm. One wave per token.
// ---------------------------------------------------------------------------
__global__ __launch_bounds__(64) void ln_kernel(
    const float* __restrict__ in, float* __restrict__ out,
    const float* __restrict__ g, const float* __restrict__ b) {
  int tokn = blockIdx.x;
  int lane = threadIdx.x;
  const float* row = in + (size_t)tokn*DM;
  float x0 = row[lane], x1 = row[lane+64], x2 = row[lane+128];
  float s = x0 + x1 + x2;
  float s2 = x0*x0 + x1*x1 + x2*x2;
#pragma unroll
  for (int off = 1; off < 64; off <<= 1) {
    s  += __shfl_xor(s,  off, 64);
    s2 += __shfl_xor(s2, off, 64);
  }
  float m = s * (1.0f/192.0f);
  float v = s2 * (1.0f/192.0f) - m*m;
  float rs = rsqrtf(v + 1e-5f);
  float* orow = out + (size_t)tokn*DM;
  orow[lane]     = (x0 - m)*rs*g[lane]     + b[lane];
  orow[lane+64]  = (x1 - m)*rs*g[lane+64]  + b[lane+64];
  orow[lane+128] = (x2 - m)*rs*g[lane+128] + b[lane+128];
}

// ---------------------------------------------------------------------------
// Patch GEMM, im2col fused into A-staging, bf16 weights:
// cur[1..][:] += X_patch @ patch_w^T. M=1568, N=192, K=768, split-K 4.
// ---------------------------------------------------------------------------
__device__ __forceinline__ float4 ldx4(const float* __restrict__ x,
                                       int pt, int hh, int w, int k) {
  int c = k >> 8, p = (k >> 4) & 15, q = k & 15;
  return *(const float4*)(x + ((size_t)(c*8 + pt)*224 + hh*16 + p)*224
                            + w*16 + q);
}

__global__ __launch_bounds__(256) void patch_gemm(
    const float* __restrict__ x, const unsigned short* __restrict__ pw,
    float* __restrict__ C) {
  __shared__ unsigned short As[64*40];
  __shared__ unsigned short Bs[64*40];
  int tid = threadIdx.x;
  int m0 = blockIdx.y * 64, n0 = blockIdx.x * 64;
  int kbase = blockIdx.z * 192;
  int wave = tid >> 6, lane = tid & 63;
  int wr = wave >> 1, wc = wave & 1;
  int srow = tid >> 2;
  int skq  = (tid & 3) * 8;
  f32x4 acc[2][2];
#pragma unroll
  for (int i = 0; i < 2; ++i)
#pragma unroll
    for (int j = 0; j < 2; ++j) acc[i][j] = (f32x4){0.f,0.f,0.f,0.f};

  int am = m0 + srow;
  bool a_ok = (am < NPATCH);
  int am_s = a_ok ? am : 0;
  int pt = am_s / 196, hw = am_s % 196, hh = hw / 14, w = hw % 14;
  int bn = n0 + srow;
  const unsigned short* bp = pw + (size_t)bn*768 + kbase + skq;
  const float4 z4 = {0.f,0.f,0.f,0.f};
  const us8 z8 = {0,0,0,0,0,0,0,0};
  int l15 = lane & 15, lk = (lane >> 4) * 8;

  const int nt = 6;   // 192/32
  float4 a0 = a_ok ? ldx4(x, pt, hh, w, kbase + skq)     : z4;
  float4 a1 = a_ok ? ldx4(x, pt, hh, w, kbase + skq + 4) : z4;
  us8 bv = *(const us8*)(bp);

  for (int i = 0; i < nt; ++i) {
    {
      short8 pa;
      pa[0]=f2bf(a0.x); pa[1]=f2bf(a0.y); pa[2]=f2bf(a0.z); pa[3]=f2bf(a0.w);
      pa[4]=f2bf(a1.x); pa[5]=f2bf(a1.y); pa[6]=f2bf(a1.z); pa[7]=f2bf(a1.w);
      *(short8*)&As[srow*40 + skq] = pa;
      *(us8*)&Bs[srow*40 + skq] = bv;
    }
    __syncthreads();
    bool pf = (i + 1 < nt);
    int kn = kbase + ((i + 1) << 5) + skq;
    a0 = (pf && a_ok) ? ldx4(x, pt, hh, w, kn)     : z4;
    a1 = (pf && a_ok) ? ldx4(x, pt, hh, w, kn + 4) : z4;
    bv = pf ? *(const us8*)(bp + ((i+1)<<5)) : z8;

    short8 af0 = *(const short8*)&As[(wr*32      + l15)*40 + lk];
    short8 af1 = *(const short8*)&As[(wr*32 + 16 + l15)*40 + lk];
    short8 bf0 = *(const short8*)&Bs[(wc*32      + l15)*40 + lk];
    short8 bf1 = *(const short8*)&Bs[(wc*32 + 16 + l15)*40 + lk];
    acc[0][0] = __builtin_amdgcn_mfma_f32_16x16x32_bf16(af0, bf0, acc[0][0], 0, 0, 0);
    acc[0][1] = __builtin_amdgcn_mfma_f32_16x16x32_bf16(af0, bf1, acc[0][1], 0, 0, 0);
    acc[1][0] = __builtin_amdgcn_mfma_f32_16x16x32_bf16(af1, bf0, acc[1][0], 0, 0, 0);
    acc[1][1] = __builtin_amdgcn_mfma_f32_16x16x32_bf16(af1, bf1, acc[1][1], 0, 0, 0);
    __syncthreads();
  }

#pragma unroll
  for (int r = 0; r < 2; ++r) {
#pragma unroll
    for (int c = 0; c < 2; ++c) {
      int col = n0 + wc*32 + c*16 + l15;
      int rowb = m0 + wr*32 + r*16 + (lane >> 4)*4;
#pragma unroll
      for (int j = 0; j < 4; ++j) {
        int row = rowb + j;
        if (row < NPATCH)
          atomicAdd(C + (size_t)row*DM + col, acc[r][c][j]);
      }
    }
  }
}

// ---------------------------------------------------------------------------
// Fused LN + xz GEMM, BN=128 (2 column tiles per block -> LN computed once
// per 128 output cols instead of per 64). grid (6, 25). ~78 KB LDS, 2/CU.
// Output xz bf16. Zeroes xdbl (bx==0).
// ---------------------------------------------------------------------------
__global__ __launch_bounds__(256) void lnxz_kernel(
    const float* __restrict__ cur, const float* __restrict__ g,
    const float* __restrict__ b, const unsigned short* __restrict__ W,
    unsigned short* __restrict__ xzb, float* __restrict__ xdbl_z) {
  __shared__ unsigned short As[64][200];
  __shared__ unsigned short Bs[128][200];
  __shared__ float gs[192], bs2[192];
  int tid = threadIdx.x;
  int m0 = blockIdx.y * 64, n0 = blockIdx.x * 128;
  int wave = tid >> 6, lane = tid & 63;
  int wr = wave >> 1, wcq = wave & 1;   // wr: row half, wcq: 64-col half
  int l15 = lane & 15, lk = (lane >> 4) * 8;

  for (int i = tid; i < 192; i += 256) { gs[i] = g[i]; bs2[i] = b[i]; }

  if (blockIdx.x == 0) {
    for (int i = tid; i < 64*11; i += 256) {
      int r = i / 11, q = i % 11;
      int row = m0 + r;
      if (row < L_TOK) {
        float4 z = {0.f,0.f,0.f,0.f};
        *(float4*)(xdbl_z + (size_t)row*XDBL_N + q*4) = z;
      }
    }
  }

  int r = tid >> 2, c0 = (tid & 3) * 48;
  float v[48];
  {
    int row = m0 + r;
    if (row < L_TOK) {
      const float* rp = cur + (size_t)row*DM + c0;
#pragma unroll
      for (int j = 0; j < 12; ++j) {
        float4 t4 = *(const float4*)(rp + j*4);
        v[j*4+0]=t4.x; v[j*4+1]=t4.y; v[j*4+2]=t4.z; v[j*4+3]=t4.w;
      }
    } else {
#pragma unroll
      for (int j = 0; j < 48; ++j) v[j] = 0.f;
    }
  }
  float s = 0.f, s2 = 0.f;
#pragma unroll
  for (int j = 0; j < 48; ++j) { s += v[j]; s2 += v[j]*v[j]; }
  s  += __shfl_xor(s, 1, 64); s2 += __shfl_xor(s2, 1, 64);
  s  += __shfl_xor(s, 2, 64); s2 += __shfl_xor(s2, 2, 64);
  float mu = s * (1.0f/192.0f);
  float var = s2 * (1.0f/192.0f) - mu*mu;
  float rsd = rsqrtf(var + 1e-5f);

  __syncthreads();
#pragma unroll
  for (int j = 0; j < 48; ++j) {
    int k = c0 + j;
    As[r][k] = f2bf((v[j] - mu)*rsd*gs[k] + bs2[k]);
  }
  // B staging: 128 rows x 192 cols bf16, us8 loads (24 per row)
  for (int i = tid; i < 128*24; i += 256) {
    int row = i / 24, q = i % 24;
    *(us8*)&Bs[row][q*8] = *(const us8*)(W + (size_t)(n0 + row)*DM + q*8);
  }
  __syncthreads();

  f32x4 acc[2][4];
#pragma unroll
  for (int i = 0; i < 2; ++i)
#pragma unroll
    for (int j = 0; j < 4; ++j) acc[i][j] = (f32x4){0.f,0.f,0.f,0.f};

#pragma unroll
  for (int kk = 0; kk < 6; ++kk) {
    short8 af0 = *(const short8*)&As[wr*32      + l15][kk*32 + lk];
    short8 af1 = *(const short8*)&As[wr*32 + 16 + l15][kk*32 + lk];
#pragma unroll
    for (int cc = 0; cc < 4; ++cc) {
      short8 bf = *(const short8*)&Bs[wcq*64 + cc*16 + l15][kk*32 + lk];
      acc[0][cc] = __builtin_amdgcn_mfma_f32_16x16x32_bf16(af0, bf, acc[0][cc], 0, 0, 0);
      acc[1][cc] = __builtin_amdgcn_mfma_f32_16x16x32_bf16(af1, bf, acc[1][cc], 0, 0, 0);
    }
  }

#pragma unroll
  for (int rr = 0; rr < 2; ++rr) {
#pragma unroll
    for (int cc = 0; cc < 4; ++cc) {
      int col = n0 + wcq*64 + cc*16 + l15;
      int rowb = m0 + wr*32 + rr*16 + (lane >> 4)*4;
#pragma unroll
      for (int j = 0; j < 4; ++j) {
        int row = rowb + j;
        if (row < L_TOK)
          xzb[(size_t)row*(2*DI) + col] = f2bf(acc[rr][cc][j]);
      }
    }
  }
}

// ---------------------------------------------------------------------------
// xdbl GEMM, conv+SiLU fused in A-staging; bf16 Wx; split-K 12 (one k-step).
// Exports u (bf16) to ucb. xdbl (f32) zero-init by lnxz. grid = (1, 25, 12).
// ---------------------------------------------------------------------------
__global__ __launch_bounds__(256) void cgemm_kernel(
    const unsigned short* __restrict__ xzb,
    const float* __restrict__ Wc, const float* __restrict__ bc,
    const unsigned short* __restrict__ B, float* __restrict__ C,
    unsigned short* __restrict__ ucb) {
  __shared__ unsigned short As[64*40];
  __shared__ unsigned short Bs[64*40];
  __shared__ float wcs[32][4];
  __shared__ float bcs[32];
  const int M = L_TOK, N = XDBL_N;
  int tid = threadIdx.x;
  int m0 = blockIdx.y * 64;
  int kbase = blockIdx.z * 32;
  int wave = tid >> 6, lane = tid & 63;
  int wr = wave >> 1, wcq = wave & 1;
  int srow = tid >> 2;
  int skq  = (tid & 3) * 8;
  if (tid < 32) {
    *(float4*)wcs[tid] = *(const float4*)(Wc + (size_t)(kbase + tid)*4);
    bcs[tid] = bc[kbase + tid];
  }

  int t = m0 + srow;
  bool a_ok = (t < M);
  bool b_ok = (srow < N);
  const unsigned short* bp = B + (size_t)srow*DI + kbase + skq;
  const us8 z8 = {0,0,0,0,0,0,0,0};
  int l15 = lane & 15, lk = (lane >> 4) * 8;
  int cg = kbase + skq;

  us8 tap[4];
#pragma unroll
  for (int j = 0; j < 4; ++j) {
    int ts = t - 3 + j;
    tap[j] = (a_ok && ts >= 0)
               ? *(const us8*)(xzb + (size_t)ts*(2*DI) + cg) : z8;
  }
  us8 bv = b_ok ? *(const us8*)(bp) : z8;
  __syncthreads();   // wcs/bcs ready

  short8 pa;
#pragma unroll
  for (int c = 0; c < 8; ++c) {
    float u = bcs[skq + c];
#pragma unroll
    for (int j = 0; j < 4; ++j)
      u = fmaf(bf2f(tap[j][c]), wcs[skq + c][j], u);
    u = u / (1.0f + expf(-u));
    pa[c] = (short)f2bf(u);
  }
  if (a_ok)
    *(short8*)(ucb + (size_t)t*DI + cg) = pa;
  *(short8*)&As[srow*40 + skq] = pa;
  *(us8*)&Bs[srow*40 + skq] = bv;
  __syncthreads();

  f32x4 acc[2][2];
#pragma unroll
  for (int i = 0; i < 2; ++i)
#pragma unroll
    for (int j = 0; j < 2; ++j) acc[i][j] = (f32x4){0.f,0.f,0.f,0.f};
  short8 af0 = *(const short8*)&As[(wr*32      + l15)*40 + lk];
  short8 af1 = *(const short8*)&As[(wr*32 + 16 + l15)*40 + lk];
  short8 bf0 = *(const short8*)&Bs[(wcq*32      + l15)*40 + lk];
  short8 bf1 = *(const short8*)&Bs[(wcq*32 + 16 + l15)*40 + lk];
  acc[0][0] = __builtin_amdgcn_mfma_f32_16x16x32_bf16(af0, bf0, acc[0][0], 0, 0, 0);
  acc[0][1] = __builtin_amdgcn_mfma_f32_16x16x32_bf16(af0, bf1, acc[0][1], 0, 0, 0);
  acc[1][0] = __builtin_amdgcn_mfma_f32_16x16x32_bf16(af1, bf0, acc[1][0], 0, 0, 0);
  acc[1][1] = __builtin_amdgcn_mfma_f32_16x16x32_bf16(af1, bf1, acc[1][1], 0, 0, 0);

#pragma unroll
  for (int r = 0; r < 2; ++r) {
#pragma unroll
    for (int c = 0; c < 2; ++c) {
      int col = wcq*32 + c*16 + l15;
      if (col >= N) continue;
      int rowb = m0 + wr*32 + r*16 + (lane >> 4)*4;
#pragma unroll
      for (int j = 0; j < 4; ++j) {
        int row = rowb + j;
        if (row >= M) continue;
        atomicAdd(C + (size_t)row*XDBL_N + col, acc[r][c][j]);
      }
    }
  }
}

// ---------------------------------------------------------------------------
// scan_p1: per-chunk local scan from zero state (CLEN=32). Exports delta bf16.
// grid = (NDG, NCHUNK) = (24, 50), 256 thr = 16d x 16n.
// ---------------------------------------------------------------------------
__global__ __launch_bounds__(256) void scan_p1(
    const unsigned short* __restrict__ ucb, const float* __restrict__ xdbl,
    const float* __restrict__ W_dt, const float* __restrict__ b_dt,
    const float* __restrict__ A_log,
    float* __restrict__ cP, float* __restrict__ cS,
    unsigned short* __restrict__ dltb) {
  __shared__ float us[CLEN][16], ds[CLEN][16], bs[CLEN][16];
  __shared__ float xd12[CLEN][12], wdt[16][12], bds[16];
  int tid = threadIdx.x;
  int dl = tid >> 4, n = tid & 15;
  int d0 = blockIdx.x * 16;
  int t0 = blockIdx.y * CLEN;
  const us8 z8 = {0,0,0,0,0,0,0,0};
  const float4 z4 = {0.f,0.f,0.f,0.f};

  for (int i = tid; i < CLEN*2; i += 256) {
    int tt = i >> 1, h = (i & 1) * 8;
    int t = t0 + tt;
    us8 v = (t < L_TOK) ? *(const us8*)(ucb + (size_t)t*DI + d0 + h) : z8;
#pragma unroll
    for (int j = 0; j < 8; ++j) us[tt][h+j] = bf2f(v[j]);
  }
  for (int i = tid; i < CLEN*7; i += 256) {
    int tt = i / 7, q = i % 7;
    int t = t0 + tt;
    float4 v = (t < L_TOK) ? *(const float4*)(xdbl + (size_t)t*XDBL_N + q*4) : z4;
    if (q < 3) {
      xd12[tt][q*4+0]=v.x; xd12[tt][q*4+1]=v.y;
      xd12[tt][q*4+2]=v.z; xd12[tt][q*4+3]=v.w;
    } else {
      int c = (q-3)*4;
      bs[tt][c+0]=v.x; bs[tt][c+1]=v.y; bs[tt][c+2]=v.z; bs[tt][c+3]=v.w;
    }
  }
  if (tid < 192) wdt[tid/12][tid%12] = W_dt[(d0 + tid/12)*DTR + tid%12];
  if (tid < 16)  bds[tid] = b_dt[d0+tid];
  __syncthreads();
  for (int i = tid; i < CLEN*16; i += 256) {
    int tt = i >> 4, dd = i & 15;
    int t = t0 + tt;
    float v = 0.0f;
    if (t < L_TOK) {
      v = bds[dd];
#pragma unroll
      for (int r = 0; r < 12; ++r) v = fmaf(xd12[tt][r], wdt[dd][r], v);
      v = (v > 20.0f) ? v : log1pf(expf(v));
      unsigned short hb = f2bf(v);
      dltb[(size_t)t*DI + d0 + dd] = hb;
      v = bf2f(hb);   // use rounded value so p1/p3 scans agree exactly
    }
    ds[tt][dd] = v;
  }
  __syncthreads();

  int d = d0 + dl;
  float a2 = -expf(A_log[d*DS + n]) * 1.44269504088896340736f;
  float s = 0.0f, P = 1.0f;
#pragma unroll 4
  for (int tt = 0; tt < CLEN; ++tt) {
    float dv = ds[tt][dl];
    float dA = exp2f(dv * a2);
    s = fmaf(dA, s, dv * bs[tt][n] * us[tt][dl]);
    P *= dA;
  }
  int o = (blockIdx.y * DI + d) * DS + n;
  cP[o] = P;
  cS[o] = s;
}

// ---------------------------------------------------------------------------
// scan_p3: carry-in combine over preceding chunks, re-scan, emit y (bf16).
// grid = (NDG, NCHUNK) = (24, 50), 256 thr.
// ---------------------------------------------------------------------------
__global__ __launch_bounds__(256) void scan_p3(
    const unsigned short* __restrict__ ucb,
    const unsigned short* __restrict__ dltb,
    const float* __restrict__ xdbl, const unsigned short* __restrict__ xzb,
    const float* __restrict__ A_log, const float* __restrict__ Dp,
    const float* __restrict__ cP, const float* __restrict__ cS,
    unsigned short* __restrict__ yyb) {
  __shared__ float us[CLEN][16], ds[CLEN][16], bs[CLEN][16];
  __shared__ float cs[CLEN][16], zs[CLEN][16];
  int tid = threadIdx.x;
  int dl = tid >> 4, n = tid & 15;
  int d0 = blockIdx.x * 16;
  int cidx = blockIdx.y;
  int t0 = cidx * CLEN;
  int nt = min(CLEN, L_TOK - t0);
  int d = d0 + dl;
  const us8 z8 = {0,0,0,0,0,0,0,0};
  const float4 z4 = {0.f,0.f,0.f,0.f};

  float s = 0.0f;
  {
    int oo = d * DS + n;
#pragma unroll 8
    for (int c2 = 0; c2 < cidx; ++c2)
      s = fmaf(cP[(size_t)c2*(DI*DS) + oo], s, cS[(size_t)c2*(DI*DS) + oo]);
  }

  for (int i = tid; i < CLEN*2; i += 256) {
    int tt = i >> 1, h = (i & 1) * 8;
    int t = t0 + tt;
    bool ok = (t < L_TOK);
    us8 vu = ok ? *(const us8*)(ucb  + (size_t)t*DI + d0 + h) : z8;
    us8 vd = ok ? *(const us8*)(dltb + (size_t)t*DI + d0 + h) : z8;
    us8 vz = ok ? *(const us8*)(xzb  + (size_t)t*(2*DI) + DI + d0 + h) : z8;
#pragma unroll
    for (int j = 0; j < 8; ++j) {
      us[tt][h+j] = bf2f(vu[j]);
      ds[tt][h+j] = bf2f(vd[j]);
      zs[tt][h+j] = bf2f(vz[j]);
    }
  }
  for (int i = tid; i < CLEN*8; i += 256) {
    int tt = i >> 3, q = i & 7;
    int t = t0 + tt;
    float4 v = (t < L_TOK)
                 ? *(const float4*)(xdbl + (size_t)t*XDBL_N + 12 + q*4) : z4;
    if (q < 4) {
      int c = q*4;
      bs[tt][c+0]=v.x; bs[tt][c+1]=v.y; bs[tt][c+2]=v.z; bs[tt][c+3]=v.w;
    } else {
      int c = (q-4)*4;
      cs[tt][c+0]=v.x; cs[tt][c+1]=v.y; cs[tt][c+2]=v.z; cs[tt][c+3]=v.w;
    }
  }
  __syncthreads();

  float a2 = -expf(A_log[d*DS + n]) * 1.44269504088896340736f;
  float dpv = Dp[d];
#pragma unroll 4
  for (int tt = 0; tt < CLEN; ++tt) {
    float dv = ds[tt][dl], uu = us[tt][dl];
    float dA = exp2f(dv * a2);
    s = fmaf(dA, s, dv * bs[tt][n] * uu);
    float p = s * cs[tt][n];
    p += __shfl_xor(p, 1, 64);
    p += __shfl_xor(p, 2, 64);
    p += __shfl_xor(p, 4, 64);
    p += __shfl_xor(p, 8, 64);
    if (n == 0 && tt < nt) {
      float z = zs[tt][dl];
      float y = fmaf(uu, dpv, p);
      y *= z / (1.0f + expf(-z));
      yyb[(size_t)(t0 + tt)*DI + d] = f2bf(y);
    }
  }
}

// ---------------------------------------------------------------------------
// out projection: cur += yy(bf16) @ W_out(bf16)^T, split-K 4, atomicAdd.
// ---------------------------------------------------------------------------
__global__ __launch_bounds__(256) void mgemm_kernel(
    const unsigned short* __restrict__ A, int lda,
    const unsigned short* __restrict__ B, int ldb,
    float* __restrict__ C, int ldc,
    int M, int N, int ksl) {
  __shared__ unsigned short As[64*40];
  __shared__ unsigned short Bs[64*40];
  int tid = threadIdx.x;
  int m0 = blockIdx.y * 64, n0 = blockIdx.x * 64;
  int kbase = blockIdx.z * ksl;
  int wave = tid >> 6, lane = tid & 63;
  int wr = wave >> 1, wc = wave & 1;
  int srow = tid >> 2;
  int skq  = (tid & 3) * 8;
  f32x4 acc[2][2];
#pragma unroll
  for (int i = 0; i < 2; ++i)
#pragma unroll
    for (int j = 0; j < 2; ++j) acc[i][j] = (f32x4){0.f,0.f,0.f,0.f};

  int am = m0 + srow;
  int bn = n0 + srow;
  bool a_ok = (am < M), b_ok = (bn < N);
  const unsigned short* ap = A + (size_t)am*lda + kbase + skq;
  const unsigned short* bp = B + (size_t)bn*ldb + kbase + skq;
  const us8 z8 = {0,0,0,0,0,0,0,0};
  int l15 = lane & 15, lk = (lane >> 4) * 8;

  int nt = ksl >> 5;
  us8 av = a_ok ? *(const us8*)(ap) : z8;
  us8 bv = b_ok ? *(const us8*)(bp) : z8;

  for (int i = 0; i < nt; ++i) {
    *(us8*)&As[srow*40 + skq] = av;
    *(us8*)&Bs[srow*40 + skq] = bv;
    __syncthreads();
    bool pf = (i + 1 < nt);
    int k0n = (i + 1) << 5;
    av = (pf && a_ok) ? *(const us8*)(ap + k0n) : z8;
    bv = (pf && b_ok) ? *(const us8*)(bp + k0n) : z8;

    short8 af0 = *(const short8*)&As[(wr*32      + l15)*40 + lk];
    short8 af1 = *(const short8*)&As[(wr*32 + 16 + l15)*40 + lk];
    short8 bf0 = *(const short8*)&Bs[(wc*32      + l15)*40 + lk];
    short8 bf1 = *(const short8*)&Bs[(wc*32 + 16 + l15)*40 + lk];
    acc[0][0] = __builtin_amdgcn_mfma_f32_16x16x32_bf16(af0, bf0, acc[0][0], 0, 0, 0);
    acc[0][1] = __builtin_amdgcn_mfma_f32_16x16x32_bf16(af0, bf1, acc[0][1], 0, 0, 0);
    acc[1][0] = __builtin_amdgcn_mfma_f32_16x16x32_bf16(af1, bf0, acc[1][0], 0, 0, 0);
    acc[1][1] = __builtin_amdgcn_mfma_f32_16x16x32_bf16(af1, bf1, acc[1][1], 0, 0, 0);
    __syncthreads();
  }

#pragma unroll
  for (int r = 0; r < 2; ++r) {
#pragma unroll
    for (int c = 0; c < 2; ++c) {
      int col = n0 + wc*32 + c*16 + l15;
      if (col >= N) continue;
      int rowb = m0 + wr*32 + r*16 + (lane >> 4)*4;
#pragma unroll
      for (int j = 0; j < 4; ++j) {
        int row = rowb + j;
        if (row >= M) continue;
        atomicAdd(C + (size_t)row*ldc + col, acc[r][c][j]);
      }
    }
  }
}

// ---------------------------------------------------------------------------
extern "C" void kernel_launch(void* const* d_in, const int* in_sizes, int n_in,
                              void* d_out, int out_size, void* d_ws, size_t ws_size,
                              hipStream_t stream) {
  const float* x       = (const float*)d_in[0];
  const float* patch_w = (const float*)d_in[1];
  const float* patch_b = (const float*)d_in[2];
  const float* cls_tok = (const float*)d_in[3];
  const float* pos_emb = (const float*)d_in[4];
  const float* ln_g    = (const float*)d_in[5];
  const float* ln_b    = (const float*)d_in[6];
  const float* W_in    = (const float*)d_in[7];
  const float* Wc      = (const float*)d_in[8];
  const float* bc      = (const float*)d_in[9];
  const float* Wx      = (const float*)d_in[10];
  const float* W_dt    = (const float*)d_in[11];
  const float* b_dt    = (const float*)d_in[12];
  const float* A_log   = (const float*)d_in[13];
  const float* Dp      = (const float*)d_in[14];
  const float* W_out   = (const float*)d_in[15];
  const float* fn_g    = (const float*)d_in[16];
  const float* fn_b    = (const float*)d_in[17];

  float* ws = (float*)d_ws;
  float* cur   = ws;                                        // 1569*192 f32
  unsigned short* xzb = (unsigned short*)(cur + L_TOK*DM);  // 1569*768 bf16
  float* xdbl  = (float*)(xzb + L_TOK*2*DI);                // 1569*44  f32
  unsigned short* ucb  = (unsigned short*)(xdbl + L_TOK*XDBL_N); // bf16
  unsigned short* dltb = ucb  + L_TOK*DI;                   // bf16
  unsigned short* yyb  = dltb + L_TOK*DI;                   // bf16
  float* cP    = (float*)(yyb + L_TOK*DI);                  // 50*6144 f32
  float* cS    = cP + NCHUNK*DI*DS;
  unsigned short* pwb  = (unsigned short*)(cS + NCHUNK*DI*DS);
  unsigned short* winb = pwb  + PW_N;
  unsigned short* wxb  = winb + WIN_N;
  unsigned short* wob  = wxb  + WX_N;

  init_kernel<<<1024, 256, 0, stream>>>(
      cls_tok, patch_b, pos_emb, cur,
      patch_w, W_in, Wx, W_out, pwb, winb, wxb, wob);
  {
    dim3 grid(DM/64, (NPATCH + 63)/64, 4);
    patch_gemm<<<grid, 256, 0, stream>>>(x, pwb, cur + DM);
  }

  for (int dep = 0; dep < DEPTH; ++dep) {
    const float* g     = ln_g  + dep*DM;
    const float* bb    = ln_b  + dep*DM;
    const unsigned short* Win_l = winb + (size_t)dep*2*DI*DM;
    const float* Wc_l  = Wc    + (size_t)dep*DI*DCONV;
    const float* bc_l  = bc    + (size_t)dep*DI;
    const unsigned short* Wx_l  = wxb + (size_t)dep*XDBL_N*DI;
    const float* Wdt_l = W_dt  + (size_t)dep*DI*DTR;
    const float* bdt_l = b_dt  + (size_t)dep*DI;
    const float* Alog_l= A_log + (size_t)dep*DI*DS;
    const float* Dp_l  = Dp    + (size_t)dep*DI;
    const unsigned short* Wout_l= wob + (size_t)dep*DM*DI;

    // xz = LN(cur) @ W_in^T (BN=128; bf16 out; zeroes xdbl)
    {
      dim3 grid((2*DI)/128, (L_TOK + 63)/64);
      lnxz_kernel<<<grid, 256, 0, stream>>>(cur, g, bb, Win_l, xzb, xdbl);
    }
    // xdbl = silu(conv(u)) @ Wx^T, split-K 12; exports ucb (bf16)
    {
      dim3 grid(1, (L_TOK + 63)/64, 12);
      cgemm_kernel<<<grid, 256, 0, stream>>>(xzb, Wc_l, bc_l, Wx_l, xdbl, ucb);
    }
    // selective scan: local (p1, exports delta bf16) then carry+emit (p3)
    {
      dim3 g1(NDG, NCHUNK);
      scan_p1<<<g1, 256, 0, stream>>>(ucb, xdbl, Wdt_l, bdt_l, Alog_l, cP, cS, dltb);
      scan_p3<<<g1, 256, 0, stream>>>(ucb, dltb, xdbl, xzb, Alog_l, Dp_l, cP, cS, yyb);
    }
    // cur += yy @ W_out^T
    {
      dim3 grid(DM/64, (L_TOK + 63)/64, 4);
      mgemm_kernel<<<grid, 256, 0, stream>>>(yyb, DI, Wout_l, DI, cur, DM,
                                             L_TOK, DM, DI/4);
    }
  }

  ln_kernel<<<L_TOK, 64, 0, stream>>>(cur, (float*)d_out, fn_g, fn_b);
}